// Round 1
// baseline (23729.558 us; speedup 1.0000x reference)
//
#include <hip/hip_runtime.h>
#include <hip/hip_bf16.h>

#define B_  512
#define T_  512
#define FS_ 64
#define FC_ 32
#define H_  256

// ws layout (bf16 element offsets)
#define WS_REC0 0        // [32 ft][8 ks][64 lane][8]
#define WS_REC1 131072
#define WS_X1P  262144   // [32][8][64][8]
#define WS_X0S  393216   // [32][2][64][8]
#define WS_X0C  425984   // [32][1][64][8]

typedef __attribute__((ext_vector_type(8))) short bfrag;
typedef __attribute__((ext_vector_type(4))) float ffrag;

__device__ __forceinline__ ffrag mfma16(bfrag a, bfrag b, ffrag c) {
    return __builtin_amdgcn_mfma_f32_16x16x32_bf16(a, b, c, 0, 0, 0);
}
__device__ __forceinline__ float fast_tanh(float x) {
    float e = __expf(2.f * x);           // inf-safe: +inf -> 1, 0 -> -1
    return 1.f - 2.f / (e + 1.f);
}
__device__ __forceinline__ float fast_sigmoid(float x) {
    return 1.f / (1.f + __expf(-x));
}

// ---------------- prepack: fp32 weights -> bf16 MFMA B-fragments ----------------
// B-frag layout for mfma_f32_16x16x32_bf16: lane holds B[k=(lane>>4)*8+j][n=lane&15]
// = W[n][k..k+7] (contiguous in source row).
__global__ __launch_bounds__(256) void prepack_kernel(
    const float* __restrict__ Win0, const float* __restrict__ Wrec0, const float* __restrict__ Wg0,
    const float* __restrict__ Win1, const float* __restrict__ Wrec1, const float* __restrict__ Wg1,
    __hip_bfloat16* __restrict__ ws)
{
    int g = blockIdx.x * 256 + threadIdx.x;
    if (g >= 55296) return;
    int lane = g & 63;
    int frag = g >> 6;               // 0..863
    int lm = lane & 15, qq = lane >> 4;
    const float* src;
    int dstoff;
    if (frag < 256) {                // rec0: even ft = Wg_h0 (cols 96..), odd = Wrec0
        int f = frag, ft = f >> 3, ks = f & 7;
        int n = (ft >> 1) * 16 + lm, kk = ks * 32 + qq * 8;
        src = (ft & 1) ? (Wrec0 + n * 256 + kk) : (Wg0 + n * 352 + 96 + kk);
        dstoff = WS_REC0 + (f * 64 + lane) * 8;
    } else if (frag < 512) {         // rec1: even = Wg_h1 (cols 256..), odd = Wrec1
        int f = frag - 256, ft = f >> 3, ks = f & 7;
        int n = (ft >> 1) * 16 + lm, kk = ks * 32 + qq * 8;
        src = (ft & 1) ? (Wrec1 + n * 256 + kk) : (Wg1 + n * 512 + 256 + kk);
        dstoff = WS_REC1 + (f * 64 + lane) * 8;
    } else if (frag < 768) {         // x1 proj: even = Win1, odd = Wg_x1 (cols 0..255)
        int f = frag - 512, ft = f >> 3, ks = f & 7;
        int n = (ft >> 1) * 16 + lm, kk = ks * 32 + qq * 8;
        src = (ft & 1) ? (Wg1 + n * 512 + kk) : (Win1 + n * 256 + kk);
        dstoff = WS_X1P + (f * 64 + lane) * 8;
    } else if (frag < 832) {         // x0 seq part (K=0..63): even = Win0, odd = Wg_x0
        int f = frag - 768, ft = f >> 1, ks = f & 1;
        int n = (ft >> 1) * 16 + lm, kk = ks * 32 + qq * 8;
        src = (ft & 1) ? (Wg0 + n * 352 + kk) : (Win0 + n * 96 + kk);
        dstoff = WS_X0S + (f * 64 + lane) * 8;
    } else {                         // x0 ctx part (K=64..95)
        int f = frag - 832, ft = f;
        int n = (ft >> 1) * 16 + lm, kk = qq * 8;
        src = (ft & 1) ? (Wg0 + n * 352 + 64 + kk) : (Win0 + n * 96 + 64 + kk);
        dstoff = WS_X0C + (f * 64 + lane) * 8;
    }
    __hip_bfloat16* d = ws + dstoff;
#pragma unroll
    for (int j = 0; j < 8; j++) d[j] = __float2bfloat16(src[j]);
}

// ---------------- main persistent kernel: 32 WGs x 16 batch rows ----------------
__global__ __launch_bounds__(512, 2) void lnn_main(
    const float* __restrict__ seq, const float* __restrict__ ctx,
    const float* __restrict__ tau0, const float* __restrict__ bg0,
    const float* __restrict__ lng0, const float* __restrict__ lnb0,
    const float* __restrict__ tau1, const float* __restrict__ bg1,
    const float* __restrict__ lng1, const float* __restrict__ lnb1,
    const float* __restrict__ cW1, const float* __restrict__ cb1,
    const float* __restrict__ cW2, const float* __restrict__ cb2,
    const __hip_bfloat16* __restrict__ ws, float* __restrict__ out)
{
    __shared__ __align__(16) float h0[16][260];
    __shared__ __align__(16) float h1[16][260];
    __shared__ __align__(16) float hn[16][260];
    __shared__ __align__(16) __hip_bfloat16 abf[2][16][272];  // A staging (hh bf16), ping-pong
    __shared__ __align__(16) __hip_bfloat16 x1bf[16][272];    // h0_new bf16 for layer1 x-proj
    __shared__ __align__(16) __hip_bfloat16 xsb[16][80];      // ctx / seq(t) staging
    __shared__ float lnw[2][256], lnbv[2][256];

    const int tid  = threadIdx.x;
    const int wave = tid >> 6, lane = tid & 63;
    const int qq   = lane >> 4, lm = lane & 15;
    const int brow = blockIdx.x * 16;

    for (int e = tid; e < 16 * 260; e += 512) { ((float*)h0)[e] = 0.f; ((float*)h1)[e] = 0.f; }
    for (int c = tid; c < 256; c += 512) {
        lnw[0][c] = lng0[c]; lnw[1][c] = lng1[c];
        lnbv[0][c] = lnb0[c]; lnbv[1][c] = lnb1[c];
    }
    // per-lane constants: wave w owns cols 32w+16p+lm, p in {0,1}
    float rtp[2][2], bgr[2][2];
    int colp[2];
#pragma unroll
    for (int p = 0; p < 2; p++) {
        int c = 32 * wave + 16 * p + lm;
        colp[p] = c;
        float t0v = tau0[c], t1v = tau1[c];
        float sp0 = fmaxf(t0v, 0.f) + logf(1.f + __expf(-fabsf(t0v)));
        float sp1 = fmaxf(t1v, 0.f) + logf(1.f + __expf(-fabsf(t1v)));
        rtp[0][p] = 1.f / (sp0 + 1.f);
        rtp[1][p] = 1.f / (sp1 + 1.f);
        bgr[0][p] = bg0[c]; bgr[1][p] = bg1[c];
    }
    // ---- ctx contribution to layer0 x-proj (constant over t) ----
    for (int e = tid; e < 16 * FC_; e += 512) {
        int r = e >> 5, c = e & 31;
        xsb[r][c] = __float2bfloat16(ctx[(brow + r) * FC_ + c]);
    }
    __syncthreads();
    float xcw[2][4], xcg[2][4];
    {
        bfrag a = *(const bfrag*)&xsb[lm][qq * 8];
#pragma unroll
        for (int p = 0; p < 2; p++) {
            int ftw = 4 * wave + 2 * p;
            ffrag zw = {0.f, 0.f, 0.f, 0.f}, zg = {0.f, 0.f, 0.f, 0.f};
            bfrag bw = *(const bfrag*)(ws + WS_X0C + (ftw * 64 + lane) * 8);
            bfrag bgf = *(const bfrag*)(ws + WS_X0C + ((ftw + 1) * 64 + lane) * 8);
            zw = mfma16(a, bw, zw);
            zg = mfma16(a, bgf, zg);
#pragma unroll
            for (int r = 0; r < 4; r++) { xcw[p][r] = zw[r]; xcg[p][r] = zg[r]; }
        }
    }
    __syncthreads();

    float xwin[2][4], xgate[2][4];

    // one RK4 layer update for this WG's 16 rows
    auto run_layer = [&](float (*hbuf)[260], const __hip_bfloat16* __restrict__ rp,
                         int l, bool tox1) {
        // stage h -> abf[0] (bf16 A for deriv 0)
        for (int e = tid; e < 4096; e += 512) {
            int r = e >> 8, c = e & 255;
            abf[0][r][c] = __float2bfloat16(hbuf[r][c]);
        }
        float hbase[2][4], hh_[2][4], ksum[2][4];
#pragma unroll
        for (int p = 0; p < 2; p++)
#pragma unroll
            for (int r = 0; r < 4; r++) {
                float v = hbuf[qq * 4 + r][colp[p]];
                hbase[p][r] = v; hh_[p][r] = v; ksum[p][r] = 0.f;
            }
#pragma unroll 1
        for (int d = 0; d < 4; d++) {
            __syncthreads();
            const __hip_bfloat16 (*A)[272] = abf[d & 1];
            ffrag ag[2], ar[2];
#pragma unroll
            for (int p = 0; p < 2; p++) {
                ag[p] = (ffrag){0.f, 0.f, 0.f, 0.f};
                ar[p] = (ffrag){0.f, 0.f, 0.f, 0.f};
            }
#pragma unroll
            for (int ks = 0; ks < 8; ks++) {
                bfrag a = *(const bfrag*)&A[lm][ks * 32 + qq * 8];
#pragma unroll
                for (int p = 0; p < 2; p++) {
                    int ftw = 4 * wave + 2 * p;
                    bfrag bg_ = *(const bfrag*)(rp + ((ftw * 8 + ks) * 64 + lane) * 8);
                    bfrag br_ = *(const bfrag*)(rp + (((ftw + 1) * 8 + ks) * 64 + lane) * 8);
                    ag[p] = mfma16(a, bg_, ag[p]);
                    ar[p] = mfma16(a, br_, ar[p]);
                }
            }
            float wsm = (d == 1 || d == 2) ? 2.f : 1.f;
            float an  = (d < 2) ? 0.5f : 1.f;
#pragma unroll
            for (int p = 0; p < 2; p++)
#pragma unroll
                for (int r = 0; r < 4; r++) {
                    float gpre = ag[p][r] + xgate[p][r];
                    float g = fast_sigmoid(fast_tanh(gpre));
                    float kd = xwin[p][r] - hh_[p][r] * rtp[l][p] + g * ar[p][r];
                    ksum[p][r] += wsm * kd;
                    if (d < 3) {
                        float hhn = hbase[p][r] + an * kd;
                        hh_[p][r] = hhn;
                        abf[(d & 1) ^ 1][qq * 4 + r][colp[p]] = __float2bfloat16(hhn);
                    } else {
                        hn[qq * 4 + r][colp[p]] = hbase[p][r] + ksum[p][r] * (1.f / 6.f);
                    }
                }
        }
        __syncthreads();
        // LayerNorm + tanh: 32 threads per row, 8 cols each
        {
            int r = tid >> 5, c0 = (tid & 31) * 8;
            float v[8], s = 0.f, s2 = 0.f;
#pragma unroll
            for (int j = 0; j < 8; j++) { v[j] = hn[r][c0 + j]; s += v[j]; s2 += v[j] * v[j]; }
#pragma unroll
            for (int m = 1; m <= 16; m <<= 1) {
                s  += __shfl_xor(s, m, 64);
                s2 += __shfl_xor(s2, m, 64);
            }
            float mean = s * (1.f / 256.f);
            float var  = s2 * (1.f / 256.f) - mean * mean;
            float rs   = rsqrtf(var + 1e-5f);
#pragma unroll
            for (int j = 0; j < 8; j++) {
                int c = c0 + j;
                float hv = fast_tanh((v[j] - mean) * rs * lnw[l][c] + lnbv[l][c]);
                hbuf[r][c] = hv;
                if (tox1) x1bf[r][c] = __float2bfloat16(hv);
            }
        }
        __syncthreads();
    };

#pragma unroll 1
    for (int t = 0; t < T_; t++) {
        // stage seq(t) -> xsb bf16
        for (int e = tid; e < 16 * FS_; e += 512) {
            int r = e >> 6, c = e & 63;
            xsb[r][c] = __float2bfloat16(seq[((size_t)(brow + r) * T_ + t) * FS_ + c]);
        }
        __syncthreads();
        // layer0 x-projection: seq part (K=64) + ctx constant
#pragma unroll
        for (int p = 0; p < 2; p++) {
            int ftw = 4 * wave + 2 * p;
            ffrag zw, zg;
#pragma unroll
            for (int r = 0; r < 4; r++) { zw[r] = xcw[p][r]; zg[r] = xcg[p][r] + bgr[0][p]; }
#pragma unroll
            for (int ks = 0; ks < 2; ks++) {
                bfrag a = *(const bfrag*)&xsb[lm][ks * 32 + qq * 8];
                bfrag bw = *(const bfrag*)(ws + WS_X0S + ((ftw * 2 + ks) * 64 + lane) * 8);
                bfrag bg_ = *(const bfrag*)(ws + WS_X0S + (((ftw + 1) * 2 + ks) * 64 + lane) * 8);
                zw = mfma16(a, bw, zw);
                zg = mfma16(a, bg_, zg);
            }
#pragma unroll
            for (int r = 0; r < 4; r++) { xwin[p][r] = zw[r]; xgate[p][r] = zg[r]; }
        }
        run_layer(h0, ws + WS_REC0, 0, true);
        // layer1 x-projection from h0_new (K=256)
#pragma unroll
        for (int p = 0; p < 2; p++) {
            int ftw = 4 * wave + 2 * p;
            ffrag zw = {0.f, 0.f, 0.f, 0.f}, zg;
#pragma unroll
            for (int r = 0; r < 4; r++) zg[r] = bgr[1][p];
#pragma unroll
            for (int ks = 0; ks < 8; ks++) {
                bfrag a = *(const bfrag*)&x1bf[lm][ks * 32 + qq * 8];
                bfrag bw = *(const bfrag*)(ws + WS_X1P + ((ftw * 8 + ks) * 64 + lane) * 8);
                bfrag bg_ = *(const bfrag*)(ws + WS_X1P + (((ftw + 1) * 8 + ks) * 64 + lane) * 8);
                zw = mfma16(a, bw, zw);
                zg = mfma16(a, bg_, zg);
            }
#pragma unroll
            for (int r = 0; r < 4; r++) { xwin[p][r] = zw[r]; xgate[p][r] = zg[r]; }
        }
        run_layer(h1, ws + WS_REC1, 1, false);
    }

    // ---- head: hid = relu(h1 @ cW1^T + cb1); out = hid @ cW2^T + cb2 ----
    {
        int r = tid >> 5, oc0 = (tid & 31) * 4;
        float hv[4];
#pragma unroll
        for (int oi = 0; oi < 4; oi++) {
            int oc = oc0 + oi;
            const float* wr = cW1 + oc * H_;
            float acc = cb1[oc];
            for (int k = 0; k < H_; k += 4) {
                acc += h1[r][k] * wr[k] + h1[r][k + 1] * wr[k + 1]
                     + h1[r][k + 2] * wr[k + 2] + h1[r][k + 3] * wr[k + 3];
            }
            hv[oi] = fmaxf(acc, 0.f);
        }
        __syncthreads();
#pragma unroll
        for (int oi = 0; oi < 4; oi++) hn[r][oc0 + oi] = hv[oi];
    }
    __syncthreads();
    if (tid < 16) {
        float acc = cb2[0];
        for (int k = 0; k < 128; k++) acc += hn[tid][k] * cW2[k];
        out[brow + tid] = acc;
    }
}

extern "C" void kernel_launch(void* const* d_in, const int* in_sizes, int n_in,
                              void* d_out, int out_size, void* d_ws, size_t ws_size,
                              hipStream_t stream) {
    const float* seq   = (const float*)d_in[0];
    const float* ctx   = (const float*)d_in[1];
    const float* tau0  = (const float*)d_in[2];
    const float* Win0  = (const float*)d_in[3];
    const float* Wrec0 = (const float*)d_in[4];
    const float* Wg0   = (const float*)d_in[5];
    const float* bg0   = (const float*)d_in[6];
    const float* lng0  = (const float*)d_in[7];
    const float* lnb0  = (const float*)d_in[8];
    const float* tau1  = (const float*)d_in[9];
    const float* Win1  = (const float*)d_in[10];
    const float* Wrec1 = (const float*)d_in[11];
    const float* Wg1   = (const float*)d_in[12];
    const float* bg1   = (const float*)d_in[13];
    const float* lng1  = (const float*)d_in[14];
    const float* lnb1  = (const float*)d_in[15];
    const float* cW1   = (const float*)d_in[16];
    const float* cb1   = (const float*)d_in[17];
    const float* cW2   = (const float*)d_in[18];
    const float* cb2   = (const float*)d_in[19];
    __hip_bfloat16* ws = (__hip_bfloat16*)d_ws;

    hipLaunchKernelGGL(prepack_kernel, dim3(216), dim3(256), 0, stream,
                       Win0, Wrec0, Wg0, Win1, Wrec1, Wg1, ws);
    hipLaunchKernelGGL(lnn_main, dim3(32), dim3(512), 0, stream,
                       seq, ctx, tau0, bg0, lng0, lnb0, tau1, bg1, lng1, lnb1,
                       cW1, cb1, cW2, cb2, ws, (float*)d_out);
}

// Round 2
// 23237.473 us; speedup vs baseline: 1.0212x; 1.0212x over previous
//
#include <hip/hip_runtime.h>
#include <hip/hip_bf16.h>

#define B_  512
#define T_  512
#define FS_ 64
#define FC_ 32
#define H_  256

// ws layout (bf16 element offsets)
#define WS_REC0 0        // [32 ft][8 ks][64 lane][8]
#define WS_REC1 131072
#define WS_X1P  262144   // [32][8][64][8]
#define WS_X0S  393216   // [32][2][64][8]
#define WS_X0C  425984   // [32][1][64][8]

typedef __attribute__((ext_vector_type(8))) short bfrag;
typedef __attribute__((ext_vector_type(4))) float ffrag;

__device__ __forceinline__ ffrag mfma16(bfrag a, bfrag b, ffrag c) {
    return __builtin_amdgcn_mfma_f32_16x16x32_bf16(a, b, c, 0, 0, 0);
}
__device__ __forceinline__ float fast_tanh(float x) {
    float e = __expf(2.f * x);           // inf-safe: +inf -> 1, 0 -> -1
    return 1.f - 2.f / (e + 1.f);
}
__device__ __forceinline__ float fast_sigmoid(float x) {
    return 1.f / (1.f + __expf(-x));
}

// ---------------- prepack: fp32 weights -> bf16 MFMA B-fragments ----------------
// B-frag layout for mfma_f32_16x16x32_bf16: lane holds B[k=(lane>>4)*8+j][n=lane&15]
// = W[n][k..k+7] (contiguous in source row).
__global__ __launch_bounds__(256) void prepack_kernel(
    const float* __restrict__ Win0, const float* __restrict__ Wrec0, const float* __restrict__ Wg0,
    const float* __restrict__ Win1, const float* __restrict__ Wrec1, const float* __restrict__ Wg1,
    __hip_bfloat16* __restrict__ ws)
{
    int g = blockIdx.x * 256 + threadIdx.x;
    if (g >= 55296) return;
    int lane = g & 63;
    int frag = g >> 6;               // 0..863
    int lm = lane & 15, qq = lane >> 4;
    const float* src;
    int dstoff;
    if (frag < 256) {                // rec0: even ft = Wg_h0 (cols 96..), odd = Wrec0
        int f = frag, ft = f >> 3, ks = f & 7;
        int n = (ft >> 1) * 16 + lm, kk = ks * 32 + qq * 8;
        src = (ft & 1) ? (Wrec0 + n * 256 + kk) : (Wg0 + n * 352 + 96 + kk);
        dstoff = WS_REC0 + (f * 64 + lane) * 8;
    } else if (frag < 512) {         // rec1: even = Wg_h1 (cols 256..), odd = Wrec1
        int f = frag - 256, ft = f >> 3, ks = f & 7;
        int n = (ft >> 1) * 16 + lm, kk = ks * 32 + qq * 8;
        src = (ft & 1) ? (Wrec1 + n * 256 + kk) : (Wg1 + n * 512 + 256 + kk);
        dstoff = WS_REC1 + (f * 64 + lane) * 8;
    } else if (frag < 768) {         // x1 proj: even = Win1, odd = Wg_x1 (cols 0..255)
        int f = frag - 512, ft = f >> 3, ks = f & 7;
        int n = (ft >> 1) * 16 + lm, kk = ks * 32 + qq * 8;
        src = (ft & 1) ? (Wg1 + n * 512 + kk) : (Win1 + n * 256 + kk);
        dstoff = WS_X1P + (f * 64 + lane) * 8;
    } else if (frag < 832) {         // x0 seq part (K=0..63): even = Win0, odd = Wg_x0
        int f = frag - 768, ft = f >> 1, ks = f & 1;
        int n = (ft >> 1) * 16 + lm, kk = ks * 32 + qq * 8;
        src = (ft & 1) ? (Wg0 + n * 352 + kk) : (Win0 + n * 96 + kk);
        dstoff = WS_X0S + (f * 64 + lane) * 8;
    } else {                         // x0 ctx part (K=64..95)
        int f = frag - 832, ft = f;
        int n = (ft >> 1) * 16 + lm, kk = qq * 8;
        src = (ft & 1) ? (Wg0 + n * 352 + 64 + kk) : (Win0 + n * 96 + 64 + kk);
        dstoff = WS_X0C + (f * 64 + lane) * 8;
    }
    __hip_bfloat16* d = ws + dstoff;
#pragma unroll
    for (int j = 0; j < 8; j++) d[j] = __float2bfloat16(src[j]);
}

// ---------------- main persistent kernel: 32 WGs x 16 batch rows ----------------
__global__ __launch_bounds__(512, 2) void lnn_main(
    const float* __restrict__ seq, const float* __restrict__ ctx,
    const float* __restrict__ tau0, const float* __restrict__ bg0,
    const float* __restrict__ lng0, const float* __restrict__ lnb0,
    const float* __restrict__ tau1, const float* __restrict__ bg1,
    const float* __restrict__ lng1, const float* __restrict__ lnb1,
    const float* __restrict__ cW1, const float* __restrict__ cb1,
    const float* __restrict__ cW2, const float* __restrict__ cb2,
    const __hip_bfloat16* __restrict__ ws, float* __restrict__ out)
{
    __shared__ __align__(16) float h0[16][260];
    __shared__ __align__(16) float h1[16][260];
    __shared__ __align__(16) float hn[16][260];
    __shared__ __align__(16) __hip_bfloat16 abf[2][16][272];  // A staging (hh bf16), ping-pong
    __shared__ __align__(16) __hip_bfloat16 x1bf[16][272];    // h0_new bf16 for layer1 x-proj
    __shared__ __align__(16) __hip_bfloat16 xsb[16][80];      // ctx / seq(t) staging
    __shared__ float lnw[2][256], lnbv[2][256];

    const int tid  = threadIdx.x;
    const int wave = tid >> 6, lane = tid & 63;
    const int qq   = lane >> 4, lm = lane & 15;
    const int brow = blockIdx.x * 16;

    for (int e = tid; e < 16 * 260; e += 512) { ((float*)h0)[e] = 0.f; ((float*)h1)[e] = 0.f; }
    for (int c = tid; c < 256; c += 512) {
        lnw[0][c] = lng0[c]; lnw[1][c] = lng1[c];
        lnbv[0][c] = lnb0[c]; lnbv[1][c] = lnb1[c];
    }
    // per-lane constants: wave w owns cols 32w+16p+lm, p in {0,1}
    float rtp[2][2], bgr[2][2];
    int colp[2];
#pragma unroll
    for (int p = 0; p < 2; p++) {
        int c = 32 * wave + 16 * p + lm;
        colp[p] = c;
        float t0v = tau0[c], t1v = tau1[c];
        float sp0 = fmaxf(t0v, 0.f) + logf(1.f + __expf(-fabsf(t0v)));
        float sp1 = fmaxf(t1v, 0.f) + logf(1.f + __expf(-fabsf(t1v)));
        rtp[0][p] = 1.f / (sp0 + 1.f);
        rtp[1][p] = 1.f / (sp1 + 1.f);
        bgr[0][p] = bg0[c]; bgr[1][p] = bg1[c];
    }
    // ---- ctx contribution to layer0 x-proj (constant over t) ----
    for (int e = tid; e < 16 * FC_; e += 512) {
        int r = e >> 5, c = e & 31;
        xsb[r][c] = __float2bfloat16(ctx[(brow + r) * FC_ + c]);
    }
    __syncthreads();
    float xcw[2][4], xcg[2][4];
    {
        bfrag a = *(const bfrag*)&xsb[lm][qq * 8];
#pragma unroll
        for (int p = 0; p < 2; p++) {
            int ftw = 4 * wave + 2 * p;
            ffrag zw = {0.f, 0.f, 0.f, 0.f}, zg = {0.f, 0.f, 0.f, 0.f};
            bfrag bw = *(const bfrag*)(ws + WS_X0C + (ftw * 64 + lane) * 8);
            bfrag bgf = *(const bfrag*)(ws + WS_X0C + ((ftw + 1) * 64 + lane) * 8);
            zw = mfma16(a, bw, zw);
            zg = mfma16(a, bgf, zg);
#pragma unroll
            for (int r = 0; r < 4; r++) { xcw[p][r] = zw[r]; xcg[p][r] = zg[r]; }
        }
    }
    __syncthreads();

    float xwin[2][4], xgate[2][4];

    // one RK4 layer update for this WG's 16 rows.
    // KEY CHANGE vs R1: the 4 RK4 derivs reuse identical weights -> load the
    // wave's 32 B-fragments (gate+rec, 2 N-tiles, 8 k-steps) into registers
    // ONCE per layer per t-step (128 VGPRs), instead of re-streaming 256 KB/WG
    // from L2 on every deriv. Loads issue at entry so latency overlaps the
    // A-staging LDS writes + barrier.
    auto run_layer = [&](float (*hbuf)[260], const __hip_bfloat16* __restrict__ rp,
                         int l, bool tox1) {
        bfrag bgc[2][8], brc[2][8];
#pragma unroll
        for (int p = 0; p < 2; p++) {
            int ftw = 4 * wave + 2 * p;
#pragma unroll
            for (int ks = 0; ks < 8; ks++) {
                bgc[p][ks] = *(const bfrag*)(rp + ((ftw * 8 + ks) * 64 + lane) * 8);
                brc[p][ks] = *(const bfrag*)(rp + (((ftw + 1) * 8 + ks) * 64 + lane) * 8);
            }
        }
        // stage h -> abf[0] (bf16 A for deriv 0)
        for (int e = tid; e < 4096; e += 512) {
            int r = e >> 8, c = e & 255;
            abf[0][r][c] = __float2bfloat16(hbuf[r][c]);
        }
        float hbase[2][4], hh_[2][4], ksum[2][4];
#pragma unroll
        for (int p = 0; p < 2; p++)
#pragma unroll
            for (int r = 0; r < 4; r++) {
                float v = hbuf[qq * 4 + r][colp[p]];
                hbase[p][r] = v; hh_[p][r] = v; ksum[p][r] = 0.f;
            }
#pragma unroll 1
        for (int d = 0; d < 4; d++) {
            __syncthreads();
            const __hip_bfloat16 (*A)[272] = abf[d & 1];
            ffrag ag[2], ar[2];
#pragma unroll
            for (int p = 0; p < 2; p++) {
                ag[p] = (ffrag){0.f, 0.f, 0.f, 0.f};
                ar[p] = (ffrag){0.f, 0.f, 0.f, 0.f};
            }
#pragma unroll
            for (int ks = 0; ks < 8; ks++) {
                bfrag a = *(const bfrag*)&A[lm][ks * 32 + qq * 8];
#pragma unroll
                for (int p = 0; p < 2; p++) {
                    ag[p] = mfma16(a, bgc[p][ks], ag[p]);
                    ar[p] = mfma16(a, brc[p][ks], ar[p]);
                }
            }
            float wsm = (d == 1 || d == 2) ? 2.f : 1.f;
            float an  = (d < 2) ? 0.5f : 1.f;
#pragma unroll
            for (int p = 0; p < 2; p++)
#pragma unroll
                for (int r = 0; r < 4; r++) {
                    float gpre = ag[p][r] + xgate[p][r];
                    float g = fast_sigmoid(fast_tanh(gpre));
                    float kd = xwin[p][r] - hh_[p][r] * rtp[l][p] + g * ar[p][r];
                    ksum[p][r] += wsm * kd;
                    if (d < 3) {
                        float hhn = hbase[p][r] + an * kd;
                        hh_[p][r] = hhn;
                        abf[(d & 1) ^ 1][qq * 4 + r][colp[p]] = __float2bfloat16(hhn);
                    } else {
                        hn[qq * 4 + r][colp[p]] = hbase[p][r] + ksum[p][r] * (1.f / 6.f);
                    }
                }
        }
        __syncthreads();
        // LayerNorm + tanh: 32 threads per row, 8 cols each
        {
            int r = tid >> 5, c0 = (tid & 31) * 8;
            float v[8], s = 0.f, s2 = 0.f;
#pragma unroll
            for (int j = 0; j < 8; j++) { v[j] = hn[r][c0 + j]; s += v[j]; s2 += v[j] * v[j]; }
#pragma unroll
            for (int m = 1; m <= 16; m <<= 1) {
                s  += __shfl_xor(s, m, 64);
                s2 += __shfl_xor(s2, m, 64);
            }
            float mean = s * (1.f / 256.f);
            float var  = s2 * (1.f / 256.f) - mean * mean;
            float rs   = rsqrtf(var + 1e-5f);
#pragma unroll
            for (int j = 0; j < 8; j++) {
                int c = c0 + j;
                float hv = fast_tanh((v[j] - mean) * rs * lnw[l][c] + lnbv[l][c]);
                hbuf[r][c] = hv;
                if (tox1) x1bf[r][c] = __float2bfloat16(hv);
            }
        }
        __syncthreads();
    };

#pragma unroll 1
    for (int t = 0; t < T_; t++) {
        // stage seq(t) -> xsb bf16
        for (int e = tid; e < 16 * FS_; e += 512) {
            int r = e >> 6, c = e & 63;
            xsb[r][c] = __float2bfloat16(seq[((size_t)(brow + r) * T_ + t) * FS_ + c]);
        }
        __syncthreads();
        // layer0 x-projection: seq part (K=64) + ctx constant
#pragma unroll
        for (int p = 0; p < 2; p++) {
            int ftw = 4 * wave + 2 * p;
            ffrag zw, zg;
#pragma unroll
            for (int r = 0; r < 4; r++) { zw[r] = xcw[p][r]; zg[r] = xcg[p][r] + bgr[0][p]; }
#pragma unroll
            for (int ks = 0; ks < 2; ks++) {
                bfrag a = *(const bfrag*)&xsb[lm][ks * 32 + qq * 8];
                bfrag bw = *(const bfrag*)(ws + WS_X0S + ((ftw * 2 + ks) * 64 + lane) * 8);
                bfrag bg_ = *(const bfrag*)(ws + WS_X0S + (((ftw + 1) * 2 + ks) * 64 + lane) * 8);
                zw = mfma16(a, bw, zw);
                zg = mfma16(a, bg_, zg);
            }
#pragma unroll
            for (int r = 0; r < 4; r++) { xwin[p][r] = zw[r]; xgate[p][r] = zg[r]; }
        }
        run_layer(h0, ws + WS_REC0, 0, true);
        // layer1 x-projection from h0_new (K=256)
#pragma unroll
        for (int p = 0; p < 2; p++) {
            int ftw = 4 * wave + 2 * p;
            ffrag zw = {0.f, 0.f, 0.f, 0.f}, zg;
#pragma unroll
            for (int r = 0; r < 4; r++) zg[r] = bgr[1][p];
#pragma unroll
            for (int ks = 0; ks < 8; ks++) {
                bfrag a = *(const bfrag*)&x1bf[lm][ks * 32 + qq * 8];
                bfrag bw = *(const bfrag*)(ws + WS_X1P + ((ftw * 8 + ks) * 64 + lane) * 8);
                bfrag bg_ = *(const bfrag*)(ws + WS_X1P + (((ftw + 1) * 8 + ks) * 64 + lane) * 8);
                zw = mfma16(a, bw, zw);
                zg = mfma16(a, bg_, zg);
            }
#pragma unroll
            for (int r = 0; r < 4; r++) { xwin[p][r] = zw[r]; xgate[p][r] = zg[r]; }
        }
        run_layer(h1, ws + WS_REC1, 1, false);
    }

    // ---- head: hid = relu(h1 @ cW1^T + cb1); out = hid @ cW2^T + cb2 ----
    {
        int r = tid >> 5, oc0 = (tid & 31) * 4;
        float hv[4];
#pragma unroll
        for (int oi = 0; oi < 4; oi++) {
            int oc = oc0 + oi;
            const float* wr = cW1 + oc * H_;
            float acc = cb1[oc];
            for (int k = 0; k < H_; k += 4) {
                acc += h1[r][k] * wr[k] + h1[r][k + 1] * wr[k + 1]
                     + h1[r][k + 2] * wr[k + 2] + h1[r][k + 3] * wr[k + 3];
            }
            hv[oi] = fmaxf(acc, 0.f);
        }
        __syncthreads();
#pragma unroll
        for (int oi = 0; oi < 4; oi++) hn[r][oc0 + oi] = hv[oi];
    }
    __syncthreads();
    if (tid < 16) {
        float acc = cb2[0];
        for (int k = 0; k < 128; k++) acc += hn[tid][k] * cW2[k];
        out[brow + tid] = acc;
    }
}

extern "C" void kernel_launch(void* const* d_in, const int* in_sizes, int n_in,
                              void* d_out, int out_size, void* d_ws, size_t ws_size,
                              hipStream_t stream) {
    const float* seq   = (const float*)d_in[0];
    const float* ctx   = (const float*)d_in[1];
    const float* tau0  = (const float*)d_in[2];
    const float* Win0  = (const float*)d_in[3];
    const float* Wrec0 = (const float*)d_in[4];
    const float* Wg0   = (const float*)d_in[5];
    const float* bg0   = (const float*)d_in[6];
    const float* lng0  = (const float*)d_in[7];
    const float* lnb0  = (const float*)d_in[8];
    const float* tau1  = (const float*)d_in[9];
    const float* Win1  = (const float*)d_in[10];
    const float* Wrec1 = (const float*)d_in[11];
    const float* Wg1   = (const float*)d_in[12];
    const float* bg1   = (const float*)d_in[13];
    const float* lng1  = (const float*)d_in[14];
    const float* lnb1  = (const float*)d_in[15];
    const float* cW1   = (const float*)d_in[16];
    const float* cb1   = (const float*)d_in[17];
    const float* cW2   = (const float*)d_in[18];
    const float* cb2   = (const float*)d_in[19];
    __hip_bfloat16* ws = (__hip_bfloat16*)d_ws;

    hipLaunchKernelGGL(prepack_kernel, dim3(216), dim3(256), 0, stream,
                       Win0, Wrec0, Wg0, Win1, Wrec1, Wg1, ws);
    hipLaunchKernelGGL(lnn_main, dim3(32), dim3(512), 0, stream,
                       seq, ctx, tau0, bg0, lng0, lnb0, tau1, bg1, lng1, lnb1,
                       cW1, cb1, cW2, cb2, ws, (float*)d_out);
}

// Round 3
// 19854.668 us; speedup vs baseline: 1.1952x; 1.1704x over previous
//
#include <hip/hip_runtime.h>
#include <hip/hip_bf16.h>

#define B_  512
#define T_  512
#define FS_ 64
#define FC_ 32
#define H_  256

// ws layout (bf16 element offsets)
#define WS_REC0 0        // [32 ft][8 ks][64 lane][8]   even ft = Wg_h, odd = Wrec
#define WS_REC1 131072
#define WS_X1P  262144   // [32][8][64][8]              even ft = Win1, odd = Wg_x1
#define WS_X0S  393216   // [32][2][64][8]              even ft = Win0, odd = Wg_x0
#define WS_X0C  425984   // [32][1][64][8]              even ft = Win0c, odd = Wg_x0c

typedef __attribute__((ext_vector_type(8))) short bfrag;
typedef __attribute__((ext_vector_type(4))) float ffrag;

__device__ __forceinline__ ffrag mfma16(bfrag a, bfrag b, ffrag c) {
    return __builtin_amdgcn_mfma_f32_16x16x32_bf16(a, b, c, 0, 0, 0);
}
// tanh(x) = 1 - 2/(exp(2x)+1); exp2+rcp HW ops (~1ulp), inf-safe both ends.
__device__ __forceinline__ float fast_tanh(float x) {
    float e = __builtin_amdgcn_exp2f(x * 2.8853901817f);   // exp(2x)
    return 1.f - 2.f * __builtin_amdgcn_rcpf(e + 1.f);
}
__device__ __forceinline__ float fast_sigmoid(float x) {
    return __builtin_amdgcn_rcpf(1.f + __builtin_amdgcn_exp2f(-1.4426950408f * x));
}

// ---------------- prepack: fp32 weights -> bf16 MFMA B-fragments ----------------
__global__ __launch_bounds__(256) void prepack_kernel(
    const float* __restrict__ Win0, const float* __restrict__ Wrec0, const float* __restrict__ Wg0,
    const float* __restrict__ Win1, const float* __restrict__ Wrec1, const float* __restrict__ Wg1,
    __hip_bfloat16* __restrict__ ws)
{
    int g = blockIdx.x * 256 + threadIdx.x;
    if (g >= 55296) return;
    int lane = g & 63;
    int frag = g >> 6;               // 0..863
    int lm = lane & 15, qq = lane >> 4;
    const float* src;
    int dstoff;
    if (frag < 256) {                // rec0: even ft = Wg_h0 (cols 96..), odd = Wrec0
        int f = frag, ft = f >> 3, ks = f & 7;
        int n = (ft >> 1) * 16 + lm, kk = ks * 32 + qq * 8;
        src = (ft & 1) ? (Wrec0 + n * 256 + kk) : (Wg0 + n * 352 + 96 + kk);
        dstoff = WS_REC0 + (f * 64 + lane) * 8;
    } else if (frag < 512) {         // rec1: even = Wg_h1 (cols 256..), odd = Wrec1
        int f = frag - 256, ft = f >> 3, ks = f & 7;
        int n = (ft >> 1) * 16 + lm, kk = ks * 32 + qq * 8;
        src = (ft & 1) ? (Wrec1 + n * 256 + kk) : (Wg1 + n * 512 + 256 + kk);
        dstoff = WS_REC1 + (f * 64 + lane) * 8;
    } else if (frag < 768) {         // x1 proj: even = Win1, odd = Wg_x1 (cols 0..255)
        int f = frag - 512, ft = f >> 3, ks = f & 7;
        int n = (ft >> 1) * 16 + lm, kk = ks * 32 + qq * 8;
        src = (ft & 1) ? (Wg1 + n * 512 + kk) : (Win1 + n * 256 + kk);
        dstoff = WS_X1P + (f * 64 + lane) * 8;
    } else if (frag < 832) {         // x0 seq part (K=0..63): even = Win0, odd = Wg_x0
        int f = frag - 768, ft = f >> 1, ks = f & 1;
        int n = (ft >> 1) * 16 + lm, kk = ks * 32 + qq * 8;
        src = (ft & 1) ? (Wg0 + n * 352 + kk) : (Win0 + n * 96 + kk);
        dstoff = WS_X0S + (f * 64 + lane) * 8;
    } else {                         // x0 ctx part (K=64..95)
        int f = frag - 832, ft = f;
        int n = (ft >> 1) * 16 + lm, kk = qq * 8;
        src = (ft & 1) ? (Wg0 + n * 352 + 64 + kk) : (Win0 + n * 96 + 64 + kk);
        dstoff = WS_X0C + (f * 64 + lane) * 8;
    }
    __hip_bfloat16* d = ws + dstoff;
#pragma unroll
    for (int j = 0; j < 8; j++) d[j] = __float2bfloat16(src[j]);
}

// ---------------- main persistent kernel: 32 WGs x 16 batch rows ----------------
// R3: 1024 threads = 16 waves (4/SIMD), wave w owns N-tile cols [16w,16w+16).
// Pointwise = 4 elems/lane; LN = one wave per row; HW rcp/exp2/rsq; LN writes
// bf16 A directly (abf[l][0] invariant) so no separate staging pass.
__global__ __launch_bounds__(1024) void lnn_main(
    const float* __restrict__ seq, const float* __restrict__ ctx,
    const float* __restrict__ tau0, const float* __restrict__ bg0,
    const float* __restrict__ lng0, const float* __restrict__ lnb0,
    const float* __restrict__ tau1, const float* __restrict__ bg1,
    const float* __restrict__ lng1, const float* __restrict__ lnb1,
    const float* __restrict__ cW1, const float* __restrict__ cb1,
    const float* __restrict__ cW2, const float* __restrict__ cb2,
    const __hip_bfloat16* __restrict__ ws, float* __restrict__ out)
{
    __shared__ __align__(16) float h0[16][260];
    __shared__ __align__(16) float h1[16][260];
    __shared__ __align__(16) float hn[16][260];
    __shared__ __align__(16) __hip_bfloat16 abf0[2][16][272];  // layer0 A ping-pong
    __shared__ __align__(16) __hip_bfloat16 abf1[2][16][272];  // layer1 A ping-pong
    __shared__ __align__(16) __hip_bfloat16 xsb[16][80];       // ctx / seq(t) staging
    __shared__ float lnw[2][256], lnbv[2][256];

    const int tid  = threadIdx.x;
    const int wave = tid >> 6, lane = tid & 63;
    const int qq   = lane >> 4, lm = lane & 15;
    const int brow = blockIdx.x * 16;
    const int col  = wave * 16 + lm;          // this lane's output column

    for (int e = tid; e < 16 * 260; e += 1024) { ((float*)h0)[e] = 0.f; ((float*)h1)[e] = 0.f; }
    for (int e = tid; e < 2 * 16 * 272; e += 1024) {
        ((__hip_bfloat16*)abf0)[e] = __float2bfloat16(0.f);
        ((__hip_bfloat16*)abf1)[e] = __float2bfloat16(0.f);
    }
    for (int c = tid; c < 256; c += 1024) {
        lnw[0][c] = lng0[c]; lnw[1][c] = lng1[c];
        lnbv[0][c] = lnb0[c]; lnbv[1][c] = lnb1[c];
    }
    // per-lane constants for column `col`
    float rtp[2], bgr[2];
    {
        float t0v = tau0[col], t1v = tau1[col];
        float sp0 = fmaxf(t0v, 0.f) + logf(1.f + __expf(-fabsf(t0v)));
        float sp1 = fmaxf(t1v, 0.f) + logf(1.f + __expf(-fabsf(t1v)));
        rtp[0] = 1.f / (sp0 + 1.f);
        rtp[1] = 1.f / (sp1 + 1.f);
        bgr[0] = bg0[col]; bgr[1] = bg1[col];
    }
    // ---- ctx contribution to layer0 x-proj (constant over t) ----
    for (int e = tid; e < 16 * FC_; e += 1024) {
        int r = e >> 5, c = e & 31;
        xsb[r][c] = __float2bfloat16(ctx[(brow + r) * FC_ + c]);
    }
    __syncthreads();
    float xcw[4], xcg[4];
    {
        bfrag a = *(const bfrag*)&xsb[lm][qq * 8];
        ffrag zw = {0.f, 0.f, 0.f, 0.f}, zg = {0.f, 0.f, 0.f, 0.f};
        bfrag bw  = *(const bfrag*)(ws + WS_X0C + ((2 * wave) * 64 + lane) * 8);
        bfrag bgf = *(const bfrag*)(ws + WS_X0C + ((2 * wave + 1) * 64 + lane) * 8);
        zw = mfma16(a, bw, zw);
        zg = mfma16(a, bgf, zg);
#pragma unroll
        for (int r = 0; r < 4; r++) { xcw[r] = zw[r]; xcg[r] = zg[r]; }
    }
    __syncthreads();   // xsb reused for seq staging

    float xwin[4], xgate[4];

    // one RK4 layer update for this WG's 16 rows
    auto run_layer = [&](float (*hbuf)[260], __hip_bfloat16 (*A2)[16][272],
                         const __hip_bfloat16* __restrict__ rp, float rtpl, int l) {
        float hbase[4], hh_[4], ksum[4];
#pragma unroll
        for (int r = 0; r < 4; r++) {
            float v = hbuf[qq * 4 + r][col];
            hbase[r] = v; hh_[r] = v; ksum[r] = 0.f;
        }
#pragma unroll 1
        for (int d = 0; d < 4; d++) {
            __syncthreads();
            const __hip_bfloat16 (*A)[272] = A2[d & 1];
            ffrag ag = {0.f, 0.f, 0.f, 0.f}, ar = {0.f, 0.f, 0.f, 0.f};
#pragma unroll
            for (int ks = 0; ks < 8; ks++) {
                bfrag a   = *(const bfrag*)&A[lm][ks * 32 + qq * 8];
                bfrag bg_ = *(const bfrag*)(rp + ((16 * wave + ks) * 64 + lane) * 8);
                bfrag br_ = *(const bfrag*)(rp + ((16 * wave + 8 + ks) * 64 + lane) * 8);
                ag = mfma16(a, bg_, ag);
                ar = mfma16(a, br_, ar);
            }
            float wsm = (d == 1 || d == 2) ? 2.f : 1.f;
            float an  = (d < 2) ? 0.5f : 1.f;
#pragma unroll
            for (int r = 0; r < 4; r++) {
                float g  = fast_sigmoid(fast_tanh(ag[r] + xgate[r]));
                float kd = xwin[r] - hh_[r] * rtpl + g * ar[r];
                ksum[r] += wsm * kd;
                if (d < 3) {
                    float hhn = hbase[r] + an * kd;
                    hh_[r] = hhn;
                    A2[(d & 1) ^ 1][qq * 4 + r][col] = __float2bfloat16(hhn);
                } else {
                    hn[qq * 4 + r][col] = hbase[r] + ksum[r] * (1.f / 6.f);
                }
            }
        }
        __syncthreads();
        // LayerNorm + tanh: wave w handles row w, 4 cols per lane
        {
            int r = wave, c0 = lane * 4;
            float4 vv = *(const float4*)&hn[r][c0];
            float v[4] = {vv.x, vv.y, vv.z, vv.w};
            float s = v[0] + v[1] + v[2] + v[3];
            float s2 = v[0]*v[0] + v[1]*v[1] + v[2]*v[2] + v[3]*v[3];
#pragma unroll
            for (int m = 1; m <= 32; m <<= 1) {
                s  += __shfl_xor(s, m, 64);
                s2 += __shfl_xor(s2, m, 64);
            }
            float mean = s * (1.f / 256.f);
            float var  = s2 * (1.f / 256.f) - mean * mean;
            float rs   = __builtin_amdgcn_rsqf(var + 1e-5f);
            float hv[4];
            __hip_bfloat16 hb[4];
#pragma unroll
            for (int j = 0; j < 4; j++) {
                int c = c0 + j;
                hv[j] = fast_tanh((v[j] - mean) * rs * lnw[l][c] + lnbv[l][c]);
                hb[j] = __float2bfloat16(hv[j]);
            }
            *(float4*)&hbuf[r][c0] = (float4){hv[0], hv[1], hv[2], hv[3]};
            *(uint2*)&A2[0][r][c0] = *(uint2*)hb;   // bf16 A for next use
        }
        __syncthreads();
    };

#pragma unroll 1
    for (int t = 0; t < T_; t++) {
        // stage seq(t) -> xsb bf16 (wave w loads row w, coalesced)
        xsb[wave][lane] = __float2bfloat16(seq[((size_t)(brow + wave) * T_ + t) * FS_ + lane]);
        __syncthreads();
        // layer0 x-projection: seq part (K=64) + ctx constant
        {
            ffrag zw, zg;
#pragma unroll
            for (int r = 0; r < 4; r++) { zw[r] = xcw[r]; zg[r] = xcg[r] + bgr[0]; }
#pragma unroll
            for (int ks = 0; ks < 2; ks++) {
                bfrag a   = *(const bfrag*)&xsb[lm][ks * 32 + qq * 8];
                bfrag bw  = *(const bfrag*)(ws + WS_X0S + ((4 * wave + ks) * 64 + lane) * 8);
                bfrag bg_ = *(const bfrag*)(ws + WS_X0S + ((4 * wave + 2 + ks) * 64 + lane) * 8);
                zw = mfma16(a, bw, zw);
                zg = mfma16(a, bg_, zg);
            }
#pragma unroll
            for (int r = 0; r < 4; r++) { xwin[r] = zw[r]; xgate[r] = zg[r]; }
        }
        run_layer(h0, abf0, ws + WS_REC0, rtp[0], 0);
        // layer1 x-projection from h0_new (bf16 already in abf0[0]), K=256
        {
            ffrag zw = {0.f, 0.f, 0.f, 0.f}, zg;
#pragma unroll
            for (int r = 0; r < 4; r++) zg[r] = bgr[1];
#pragma unroll
            for (int ks = 0; ks < 8; ks++) {
                bfrag a   = *(const bfrag*)&abf0[0][lm][ks * 32 + qq * 8];
                bfrag bw  = *(const bfrag*)(ws + WS_X1P + ((16 * wave + ks) * 64 + lane) * 8);
                bfrag bg_ = *(const bfrag*)(ws + WS_X1P + ((16 * wave + 8 + ks) * 64 + lane) * 8);
                zw = mfma16(a, bw, zw);
                zg = mfma16(a, bg_, zg);
            }
#pragma unroll
            for (int r = 0; r < 4; r++) { xwin[r] = zw[r]; xgate[r] = zg[r]; }
        }
        run_layer(h1, abf1, ws + WS_REC1, rtp[1], 1);
    }

    // ---- head: hid = relu(h1 @ cW1^T + cb1); out = hid @ cW2^T + cb2 ----
    {
        int r = wave;                 // wave w handles batch row w; lane -> 2 outputs
        float acc0 = cb1[lane], acc1 = cb1[lane + 64];
        const float* w0 = cW1 + (size_t)lane * H_;
        const float* w1 = cW1 + (size_t)(lane + 64) * H_;
        for (int k = 0; k < H_; k += 4) {
            float4 hv = *(const float4*)&h1[r][k];
            acc0 += hv.x * w0[k] + hv.y * w0[k+1] + hv.z * w0[k+2] + hv.w * w0[k+3];
            acc1 += hv.x * w1[k] + hv.y * w1[k+1] + hv.z * w1[k+2] + hv.w * w1[k+3];
        }
        __syncthreads();
        hn[r][lane]      = fmaxf(acc0, 0.f);
        hn[r][lane + 64] = fmaxf(acc1, 0.f);
    }
    __syncthreads();
    if (tid < 16) {
        float acc = cb2[0];
        for (int k = 0; k < 128; k++) acc += hn[tid][k] * cW2[k];
        out[brow + tid] = acc;
    }
}

extern "C" void kernel_launch(void* const* d_in, const int* in_sizes, int n_in,
                              void* d_out, int out_size, void* d_ws, size_t ws_size,
                              hipStream_t stream) {
    const float* seq   = (const float*)d_in[0];
    const float* ctx   = (const float*)d_in[1];
    const float* tau0  = (const float*)d_in[2];
    const float* Win0  = (const float*)d_in[3];
    const float* Wrec0 = (const float*)d_in[4];
    const float* Wg0   = (const float*)d_in[5];
    const float* bg0   = (const float*)d_in[6];
    const float* lng0  = (const float*)d_in[7];
    const float* lnb0  = (const float*)d_in[8];
    const float* tau1  = (const float*)d_in[9];
    const float* Win1  = (const float*)d_in[10];
    const float* Wrec1 = (const float*)d_in[11];
    const float* Wg1   = (const float*)d_in[12];
    const float* bg1   = (const float*)d_in[13];
    const float* lng1  = (const float*)d_in[14];
    const float* lnb1  = (const float*)d_in[15];
    const float* cW1   = (const float*)d_in[16];
    const float* cb1   = (const float*)d_in[17];
    const float* cW2   = (const float*)d_in[18];
    const float* cb2   = (const float*)d_in[19];
    __hip_bfloat16* ws = (__hip_bfloat16*)d_ws;

    hipLaunchKernelGGL(prepack_kernel, dim3(216), dim3(256), 0, stream,
                       Win0, Wrec0, Wg0, Win1, Wrec1, Wg1, ws);
    hipLaunchKernelGGL(lnn_main, dim3(32), dim3(1024), 0, stream,
                       seq, ctx, tau0, bg0, lng0, lnb0, tau1, bg1, lng1, lnb1,
                       cW1, cb1, cW2, cb2, ws, (float*)d_out);
}

// Round 4
// 19824.873 us; speedup vs baseline: 1.1970x; 1.0015x over previous
//
#include <hip/hip_runtime.h>
#include <hip/hip_bf16.h>

#define B_  512
#define T_  512
#define FS_ 64
#define FC_ 32
#define H_  256

// ws layout (bf16 element offsets)
#define WS_REC0 0        // [32 ft][8 ks][64 lane][8]   even ft = Wg_h, odd = Wrec
#define WS_REC1 131072
#define WS_X1P  262144   // [32][8][64][8]              even ft = Win1, odd = Wg_x1
#define WS_X0S  393216   // [32][2][64][8]              even ft = Win0, odd = Wg_x0
#define WS_X0C  425984   // [32][1][64][8]              even ft = Win0c, odd = Wg_x0c

typedef __attribute__((ext_vector_type(8))) short bfrag;
typedef __attribute__((ext_vector_type(4))) float ffrag;

__device__ __forceinline__ ffrag mfma16(bfrag a, bfrag b, ffrag c) {
    return __builtin_amdgcn_mfma_f32_16x16x32_bf16(a, b, c, 0, 0, 0);
}
// tanh(x) = 1 - 2/(exp(2x)+1); exp2+rcp HW ops (~1ulp), inf-safe both ends.
__device__ __forceinline__ float fast_tanh(float x) {
    float e = __builtin_amdgcn_exp2f(x * 2.8853901817f);   // exp(2x)
    return 1.f - 2.f * __builtin_amdgcn_rcpf(e + 1.f);
}
__device__ __forceinline__ float fast_sigmoid(float x) {
    return __builtin_amdgcn_rcpf(1.f + __builtin_amdgcn_exp2f(-1.4426950408f * x));
}

// ---------------- prepack: fp32 weights -> bf16 MFMA B-fragments ----------------
__global__ __launch_bounds__(256) void prepack_kernel(
    const float* __restrict__ Win0, const float* __restrict__ Wrec0, const float* __restrict__ Wg0,
    const float* __restrict__ Win1, const float* __restrict__ Wrec1, const float* __restrict__ Wg1,
    __hip_bfloat16* __restrict__ ws)
{
    int g = blockIdx.x * 256 + threadIdx.x;
    if (g >= 55296) return;
    int lane = g & 63;
    int frag = g >> 6;               // 0..863
    int lm = lane & 15, qq = lane >> 4;
    const float* src;
    int dstoff;
    if (frag < 256) {                // rec0: even ft = Wg_h0 (cols 96..), odd = Wrec0
        int f = frag, ft = f >> 3, ks = f & 7;
        int n = (ft >> 1) * 16 + lm, kk = ks * 32 + qq * 8;
        src = (ft & 1) ? (Wrec0 + n * 256 + kk) : (Wg0 + n * 352 + 96 + kk);
        dstoff = WS_REC0 + (f * 64 + lane) * 8;
    } else if (frag < 512) {         // rec1: even = Wg_h1 (cols 256..), odd = Wrec1
        int f = frag - 256, ft = f >> 3, ks = f & 7;
        int n = (ft >> 1) * 16 + lm, kk = ks * 32 + qq * 8;
        src = (ft & 1) ? (Wrec1 + n * 256 + kk) : (Wg1 + n * 512 + 256 + kk);
        dstoff = WS_REC1 + (f * 64 + lane) * 8;
    } else if (frag < 768) {         // x1 proj: even = Win1, odd = Wg_x1 (cols 0..255)
        int f = frag - 512, ft = f >> 3, ks = f & 7;
        int n = (ft >> 1) * 16 + lm, kk = ks * 32 + qq * 8;
        src = (ft & 1) ? (Wg1 + n * 512 + kk) : (Win1 + n * 256 + kk);
        dstoff = WS_X1P + (f * 64 + lane) * 8;
    } else if (frag < 832) {         // x0 seq part (K=0..63): even = Win0, odd = Wg_x0
        int f = frag - 768, ft = f >> 1, ks = f & 1;
        int n = (ft >> 1) * 16 + lm, kk = ks * 32 + qq * 8;
        src = (ft & 1) ? (Wg0 + n * 352 + kk) : (Win0 + n * 96 + kk);
        dstoff = WS_X0S + (f * 64 + lane) * 8;
    } else {                         // x0 ctx part (K=64..95)
        int f = frag - 832, ft = f;
        int n = (ft >> 1) * 16 + lm, kk = qq * 8;
        src = (ft & 1) ? (Wg0 + n * 352 + 64 + kk) : (Win0 + n * 96 + 64 + kk);
        dstoff = WS_X0C + (f * 64 + lane) * 8;
    }
    __hip_bfloat16* d = ws + dstoff;
#pragma unroll
    for (int j = 0; j < 8; j++) d[j] = __float2bfloat16(src[j]);
}

// ---------------- main persistent kernel: 32 WGs x 16 batch rows ----------------
// R4: launch_bounds(1024,4) pins 4 waves/SIMD (VGPR cap 128; LDS already caps us
// at 1 block/CU, so minimizing below 128 buys nothing). Each wave register-caches
// its 16 rec B-fragments (64 VGPRs) ONCE per layer per t-step and reuses them
// across all 4 RK4 derivs -> per-step L2 weight traffic 2.4 MB -> 0.83 MB.
__global__ __launch_bounds__(1024, 4) void lnn_main(
    const float* __restrict__ seq, const float* __restrict__ ctx,
    const float* __restrict__ tau0, const float* __restrict__ bg0,
    const float* __restrict__ lng0, const float* __restrict__ lnb0,
    const float* __restrict__ tau1, const float* __restrict__ bg1,
    const float* __restrict__ lng1, const float* __restrict__ lnb1,
    const float* __restrict__ cW1, const float* __restrict__ cb1,
    const float* __restrict__ cW2, const float* __restrict__ cb2,
    const __hip_bfloat16* __restrict__ ws, float* __restrict__ out)
{
    __shared__ __align__(16) float h0[16][260];
    __shared__ __align__(16) float h1[16][260];
    __shared__ __align__(16) float hn[16][260];
    __shared__ __align__(16) __hip_bfloat16 abf0[2][16][272];  // layer0 A ping-pong
    __shared__ __align__(16) __hip_bfloat16 abf1[2][16][272];  // layer1 A ping-pong
    __shared__ __align__(16) __hip_bfloat16 xsb[16][80];       // ctx / seq(t) staging
    __shared__ float lnw[2][256], lnbv[2][256];

    const int tid  = threadIdx.x;
    const int wave = tid >> 6, lane = tid & 63;
    const int qq   = lane >> 4, lm = lane & 15;
    const int brow = blockIdx.x * 16;
    const int col  = wave * 16 + lm;          // this lane's output column

    for (int e = tid; e < 16 * 260; e += 1024) { ((float*)h0)[e] = 0.f; ((float*)h1)[e] = 0.f; }
    for (int e = tid; e < 2 * 16 * 272; e += 1024) {
        ((__hip_bfloat16*)abf0)[e] = __float2bfloat16(0.f);
        ((__hip_bfloat16*)abf1)[e] = __float2bfloat16(0.f);
    }
    for (int c = tid; c < 256; c += 1024) {
        lnw[0][c] = lng0[c]; lnw[1][c] = lng1[c];
        lnbv[0][c] = lnb0[c]; lnbv[1][c] = lnb1[c];
    }
    // per-lane constants for column `col`
    float rtp[2], bgr[2];
    {
        float t0v = tau0[col], t1v = tau1[col];
        float sp0 = fmaxf(t0v, 0.f) + logf(1.f + __expf(-fabsf(t0v)));
        float sp1 = fmaxf(t1v, 0.f) + logf(1.f + __expf(-fabsf(t1v)));
        rtp[0] = 1.f / (sp0 + 1.f);
        rtp[1] = 1.f / (sp1 + 1.f);
        bgr[0] = bg0[col]; bgr[1] = bg1[col];
    }
    // ---- ctx contribution to layer0 x-proj (constant over t) ----
    for (int e = tid; e < 16 * FC_; e += 1024) {
        int r = e >> 5, c = e & 31;
        xsb[r][c] = __float2bfloat16(ctx[(brow + r) * FC_ + c]);
    }
    __syncthreads();
    float xcw[4], xcg[4];
    {
        bfrag a = *(const bfrag*)&xsb[lm][qq * 8];
        ffrag zw = {0.f, 0.f, 0.f, 0.f}, zg = {0.f, 0.f, 0.f, 0.f};
        bfrag bw  = *(const bfrag*)(ws + WS_X0C + ((2 * wave) * 64 + lane) * 8);
        bfrag bgf = *(const bfrag*)(ws + WS_X0C + ((2 * wave + 1) * 64 + lane) * 8);
        zw = mfma16(a, bw, zw);
        zg = mfma16(a, bgf, zg);
#pragma unroll
        for (int r = 0; r < 4; r++) { xcw[r] = zw[r]; xcg[r] = zg[r]; }
    }
    __syncthreads();   // xsb reused for seq staging

    float xwin[4], xgate[4];

    // one RK4 layer update for this WG's 16 rows.
    // Rec weights register-cached at entry (16 frags = 64 VGPRs), reused x4.
    auto run_layer = [&](float (*hbuf)[260], __hip_bfloat16 (*A2)[16][272],
                         const __hip_bfloat16* __restrict__ rp, float rtpl, int l) {
        bfrag bgc[8], brc[8];
#pragma unroll
        for (int ks = 0; ks < 8; ks++) {
            bgc[ks] = *(const bfrag*)(rp + ((16 * wave + ks) * 64 + lane) * 8);
            brc[ks] = *(const bfrag*)(rp + ((16 * wave + 8 + ks) * 64 + lane) * 8);
        }
        float hbase[4], hh_[4], ksum[4];
#pragma unroll
        for (int r = 0; r < 4; r++) {
            float v = hbuf[qq * 4 + r][col];
            hbase[r] = v; hh_[r] = v; ksum[r] = 0.f;
        }
#pragma unroll 1
        for (int d = 0; d < 4; d++) {
            __syncthreads();
            const __hip_bfloat16 (*A)[272] = A2[d & 1];
            ffrag ag = {0.f, 0.f, 0.f, 0.f}, ar = {0.f, 0.f, 0.f, 0.f};
#pragma unroll
            for (int ks = 0; ks < 8; ks++) {
                bfrag a = *(const bfrag*)&A[lm][ks * 32 + qq * 8];
                ag = mfma16(a, bgc[ks], ag);
                ar = mfma16(a, brc[ks], ar);
            }
            float wsm = (d == 1 || d == 2) ? 2.f : 1.f;
            float an  = (d < 2) ? 0.5f : 1.f;
#pragma unroll
            for (int r = 0; r < 4; r++) {
                float g  = fast_sigmoid(fast_tanh(ag[r] + xgate[r]));
                float kd = xwin[r] - hh_[r] * rtpl + g * ar[r];
                ksum[r] += wsm * kd;
                if (d < 3) {
                    float hhn = hbase[r] + an * kd;
                    hh_[r] = hhn;
                    A2[(d & 1) ^ 1][qq * 4 + r][col] = __float2bfloat16(hhn);
                } else {
                    hn[qq * 4 + r][col] = hbase[r] + ksum[r] * (1.f / 6.f);
                }
            }
        }
        __syncthreads();
        // LayerNorm + tanh: wave w handles row w, 4 cols per lane
        {
            int r = wave, c0 = lane * 4;
            float4 vv = *(const float4*)&hn[r][c0];
            float v[4] = {vv.x, vv.y, vv.z, vv.w};
            float s = v[0] + v[1] + v[2] + v[3];
            float s2 = v[0]*v[0] + v[1]*v[1] + v[2]*v[2] + v[3]*v[3];
#pragma unroll
            for (int m = 1; m <= 32; m <<= 1) {
                s  += __shfl_xor(s, m, 64);
                s2 += __shfl_xor(s2, m, 64);
            }
            float mean = s * (1.f / 256.f);
            float var  = s2 * (1.f / 256.f) - mean * mean;
            float rs   = __builtin_amdgcn_rsqf(var + 1e-5f);
            float hv[4];
            __hip_bfloat16 hb[4];
#pragma unroll
            for (int j = 0; j < 4; j++) {
                int c = c0 + j;
                hv[j] = fast_tanh((v[j] - mean) * rs * lnw[l][c] + lnbv[l][c]);
                hb[j] = __float2bfloat16(hv[j]);
            }
            *(float4*)&hbuf[r][c0] = (float4){hv[0], hv[1], hv[2], hv[3]};
            *(uint2*)&A2[0][r][c0] = *(uint2*)hb;   // bf16 A for next use
        }
        __syncthreads();
    };

#pragma unroll 1
    for (int t = 0; t < T_; t++) {
        // stage seq(t) -> xsb bf16 (wave w loads row w, coalesced)
        xsb[wave][lane] = __float2bfloat16(seq[((size_t)(brow + wave) * T_ + t) * FS_ + lane]);
        __syncthreads();
        // layer0 x-projection: seq part (K=64) + ctx constant
        {
            ffrag zw, zg;
#pragma unroll
            for (int r = 0; r < 4; r++) { zw[r] = xcw[r]; zg[r] = xcg[r] + bgr[0]; }
#pragma unroll
            for (int ks = 0; ks < 2; ks++) {
                bfrag a   = *(const bfrag*)&xsb[lm][ks * 32 + qq * 8];
                bfrag bw  = *(const bfrag*)(ws + WS_X0S + ((4 * wave + ks) * 64 + lane) * 8);
                bfrag bg_ = *(const bfrag*)(ws + WS_X0S + ((4 * wave + 2 + ks) * 64 + lane) * 8);
                zw = mfma16(a, bw, zw);
                zg = mfma16(a, bg_, zg);
            }
#pragma unroll
            for (int r = 0; r < 4; r++) { xwin[r] = zw[r]; xgate[r] = zg[r]; }
        }
        run_layer(h0, abf0, ws + WS_REC0, rtp[0], 0);
        // layer1 x-projection from h0_new (bf16 already in abf0[0]), K=256
        {
            ffrag zw = {0.f, 0.f, 0.f, 0.f}, zg;
#pragma unroll
            for (int r = 0; r < 4; r++) zg[r] = bgr[1];
#pragma unroll
            for (int ks = 0; ks < 8; ks++) {
                bfrag a   = *(const bfrag*)&abf0[0][lm][ks * 32 + qq * 8];
                bfrag bw  = *(const bfrag*)(ws + WS_X1P + ((16 * wave + ks) * 64 + lane) * 8);
                bfrag bg_ = *(const bfrag*)(ws + WS_X1P + ((16 * wave + 8 + ks) * 64 + lane) * 8);
                zw = mfma16(a, bw, zw);
                zg = mfma16(a, bg_, zg);
            }
#pragma unroll
            for (int r = 0; r < 4; r++) { xwin[r] = zw[r]; xgate[r] = zg[r]; }
        }
        run_layer(h1, abf1, ws + WS_REC1, rtp[1], 1);
    }

    // ---- head: hid = relu(h1 @ cW1^T + cb1); out = hid @ cW2^T + cb2 ----
    {
        int r = wave;                 // wave w handles batch row w; lane -> 2 outputs
        float acc0 = cb1[lane], acc1 = cb1[lane + 64];
        const float* w0 = cW1 + (size_t)lane * H_;
        const float* w1 = cW1 + (size_t)(lane + 64) * H_;
        for (int k = 0; k < H_; k += 4) {
            float4 hv = *(const float4*)&h1[r][k];
            acc0 += hv.x * w0[k] + hv.y * w0[k+1] + hv.z * w0[k+2] + hv.w * w0[k+3];
            acc1 += hv.x * w1[k] + hv.y * w1[k+1] + hv.z * w1[k+2] + hv.w * w1[k+3];
        }
        __syncthreads();
        hn[r][lane]      = fmaxf(acc0, 0.f);
        hn[r][lane + 64] = fmaxf(acc1, 0.f);
    }
    __syncthreads();
    if (tid < 16) {
        float acc = cb2[0];
        for (int k = 0; k < 128; k++) acc += hn[tid][k] * cW2[k];
        out[brow + tid] = acc;
    }
}

extern "C" void kernel_launch(void* const* d_in, const int* in_sizes, int n_in,
                              void* d_out, int out_size, void* d_ws, size_t ws_size,
                              hipStream_t stream) {
    const float* seq   = (const float*)d_in[0];
    const float* ctx   = (const float*)d_in[1];
    const float* tau0  = (const float*)d_in[2];
    const float* Win0  = (const float*)d_in[3];
    const float* Wrec0 = (const float*)d_in[4];
    const float* Wg0   = (const float*)d_in[5];
    const float* bg0   = (const float*)d_in[6];
    const float* lng0  = (const float*)d_in[7];
    const float* lnb0  = (const float*)d_in[8];
    const float* tau1  = (const float*)d_in[9];
    const float* Win1  = (const float*)d_in[10];
    const float* Wrec1 = (const float*)d_in[11];
    const float* Wg1   = (const float*)d_in[12];
    const float* bg1   = (const float*)d_in[13];
    const float* lng1  = (const float*)d_in[14];
    const float* lnb1  = (const float*)d_in[15];
    const float* cW1   = (const float*)d_in[16];
    const float* cb1   = (const float*)d_in[17];
    const float* cW2   = (const float*)d_in[18];
    const float* cb2   = (const float*)d_in[19];
    __hip_bfloat16* ws = (__hip_bfloat16*)d_ws;

    hipLaunchKernelGGL(prepack_kernel, dim3(216), dim3(256), 0, stream,
                       Win0, Wrec0, Wg0, Win1, Wrec1, Wg1, ws);
    hipLaunchKernelGGL(lnn_main, dim3(32), dim3(1024), 0, stream,
                       seq, ctx, tau0, bg0, lng0, lnb0, tau1, bg1, lng1, lnb1,
                       cW1, cb1, cW2, cb2, ws, (float*)d_out);
}

// Round 5
// 16213.371 us; speedup vs baseline: 1.4636x; 1.2227x over previous
//
#include <hip/hip_runtime.h>
#include <hip/hip_bf16.h>

#define B_  512
#define T_  512
#define FS_ 64
#define FC_ 32
#define H_  256
#define APAD 264   // bf16 A-tile row stride: 132 words = 4 mod 32 -> 2-way (free) on b128 reads

// ws layout (bf16 element offsets)
#define WS_REC0 0        // [32 ft][8 ks][64 lane][8]   even ft = Wg_h, odd = Wrec
#define WS_REC1 131072
#define WS_X1P  262144   // [32][8][64][8]              even ft = Win1, odd = Wg_x1
#define WS_X0S  393216   // [32][2][64][8]              even ft = Win0, odd = Wg_x0
#define WS_X0C  425984   // [32][1][64][8]              even ft = Win0c, odd = Wg_x0c

typedef __attribute__((ext_vector_type(8))) short bfrag;
typedef __attribute__((ext_vector_type(4))) float ffrag;

__device__ __forceinline__ ffrag mfma16(bfrag a, bfrag b, ffrag c) {
    return __builtin_amdgcn_mfma_f32_16x16x32_bf16(a, b, c, 0, 0, 0);
}
// tanh(x) = 1 - 2/(exp(2x)+1); exp2+rcp HW ops (~1ulp), inf-safe both ends.
__device__ __forceinline__ float fast_tanh(float x) {
    float e = __builtin_amdgcn_exp2f(x * 2.8853901817f);   // exp(2x)
    return 1.f - 2.f * __builtin_amdgcn_rcpf(e + 1.f);
}
__device__ __forceinline__ float fast_sigmoid(float x) {
    return __builtin_amdgcn_rcpf(1.f + __builtin_amdgcn_exp2f(-1.4426950408f * x));
}

// ---------------- prepack: fp32 weights -> bf16 MFMA B-fragments ----------------
__global__ __launch_bounds__(256) void prepack_kernel(
    const float* __restrict__ Win0, const float* __restrict__ Wrec0, const float* __restrict__ Wg0,
    const float* __restrict__ Win1, const float* __restrict__ Wrec1, const float* __restrict__ Wg1,
    __hip_bfloat16* __restrict__ ws)
{
    int g = blockIdx.x * 256 + threadIdx.x;
    if (g >= 55296) return;
    int lane = g & 63;
    int frag = g >> 6;               // 0..863
    int lm = lane & 15, qq = lane >> 4;
    const float* src;
    int dstoff;
    if (frag < 256) {                // rec0: even ft = Wg_h0 (cols 96..), odd = Wrec0
        int f = frag, ft = f >> 3, ks = f & 7;
        int n = (ft >> 1) * 16 + lm, kk = ks * 32 + qq * 8;
        src = (ft & 1) ? (Wrec0 + n * 256 + kk) : (Wg0 + n * 352 + 96 + kk);
        dstoff = WS_REC0 + (f * 64 + lane) * 8;
    } else if (frag < 512) {         // rec1: even = Wg_h1 (cols 256..), odd = Wrec1
        int f = frag - 256, ft = f >> 3, ks = f & 7;
        int n = (ft >> 1) * 16 + lm, kk = ks * 32 + qq * 8;
        src = (ft & 1) ? (Wrec1 + n * 256 + kk) : (Wg1 + n * 512 + 256 + kk);
        dstoff = WS_REC1 + (f * 64 + lane) * 8;
    } else if (frag < 768) {         // x1 proj: even = Win1, odd = Wg_x1 (cols 0..255)
        int f = frag - 512, ft = f >> 3, ks = f & 7;
        int n = (ft >> 1) * 16 + lm, kk = ks * 32 + qq * 8;
        src = (ft & 1) ? (Wg1 + n * 512 + kk) : (Win1 + n * 256 + kk);
        dstoff = WS_X1P + (f * 64 + lane) * 8;
    } else if (frag < 832) {         // x0 seq part (K=0..63): even = Win0, odd = Wg_x0
        int f = frag - 768, ft = f >> 1, ks = f & 1;
        int n = (ft >> 1) * 16 + lm, kk = ks * 32 + qq * 8;
        src = (ft & 1) ? (Wg0 + n * 352 + kk) : (Win0 + n * 96 + kk);
        dstoff = WS_X0S + (f * 64 + lane) * 8;
    } else {                         // x0 ctx part (K=64..95)
        int f = frag - 832, ft = f;
        int n = (ft >> 1) * 16 + lm, kk = qq * 8;
        src = (ft & 1) ? (Wg0 + n * 352 + 64 + kk) : (Win0 + n * 96 + 64 + kk);
        dstoff = WS_X0C + (f * 64 + lane) * 8;
    }
    __hip_bfloat16* d = ws + dstoff;
#pragma unroll
    for (int j = 0; j < 8; j++) d[j] = __float2bfloat16(src[j]);
}

// ---------------- main persistent kernel: 32 WGs x 16 batch rows ----------------
// R5: (a) asm-pin the per-layer 16-frag weight cache so the allocator cannot
// rematerialize the loads inside the deriv loop (R2/R4 failure mode: VGPR stayed
// 64 and weights re-streamed every deriv); (b) APAD 264 kills the 4-way LDS bank
// conflict on A-frag ds_read_b128.
__global__ __launch_bounds__(1024, 4) void lnn_main(
    const float* __restrict__ seq, const float* __restrict__ ctx,
    const float* __restrict__ tau0, const float* __restrict__ bg0,
    const float* __restrict__ lng0, const float* __restrict__ lnb0,
    const float* __restrict__ tau1, const float* __restrict__ bg1,
    const float* __restrict__ lng1, const float* __restrict__ lnb1,
    const float* __restrict__ cW1, const float* __restrict__ cb1,
    const float* __restrict__ cW2, const float* __restrict__ cb2,
    const __hip_bfloat16* __restrict__ ws, float* __restrict__ out)
{
    __shared__ __align__(16) float h0[16][260];
    __shared__ __align__(16) float h1[16][260];
    __shared__ __align__(16) float hn[16][260];
    __shared__ __align__(16) __hip_bfloat16 abf0[2][16][APAD];  // layer0 A ping-pong
    __shared__ __align__(16) __hip_bfloat16 abf1[2][16][APAD];  // layer1 A ping-pong
    __shared__ __align__(16) __hip_bfloat16 xsb[16][80];        // ctx / seq(t) staging
    __shared__ float lnw[2][256], lnbv[2][256];

    const int tid  = threadIdx.x;
    const int wave = tid >> 6, lane = tid & 63;
    const int qq   = lane >> 4, lm = lane & 15;
    const int brow = blockIdx.x * 16;
    const int col  = wave * 16 + lm;          // this lane's output column

    for (int e = tid; e < 16 * 260; e += 1024) { ((float*)h0)[e] = 0.f; ((float*)h1)[e] = 0.f; }
    for (int e = tid; e < 2 * 16 * APAD; e += 1024) {
        ((__hip_bfloat16*)abf0)[e] = __float2bfloat16(0.f);
        ((__hip_bfloat16*)abf1)[e] = __float2bfloat16(0.f);
    }
    for (int c = tid; c < 256; c += 1024) {
        lnw[0][c] = lng0[c]; lnw[1][c] = lng1[c];
        lnbv[0][c] = lnb0[c]; lnbv[1][c] = lnb1[c];
    }
    // per-lane constants for column `col`
    float rtp[2], bgr[2];
    {
        float t0v = tau0[col], t1v = tau1[col];
        float sp0 = fmaxf(t0v, 0.f) + logf(1.f + __expf(-fabsf(t0v)));
        float sp1 = fmaxf(t1v, 0.f) + logf(1.f + __expf(-fabsf(t1v)));
        rtp[0] = 1.f / (sp0 + 1.f);
        rtp[1] = 1.f / (sp1 + 1.f);
        bgr[0] = bg0[col]; bgr[1] = bg1[col];
    }
    // ---- ctx contribution to layer0 x-proj (constant over t) ----
    for (int e = tid; e < 16 * FC_; e += 1024) {
        int r = e >> 5, c = e & 31;
        xsb[r][c] = __float2bfloat16(ctx[(brow + r) * FC_ + c]);
    }
    __syncthreads();
    float xcw[4], xcg[4];
    {
        bfrag a = *(const bfrag*)&xsb[lm][qq * 8];
        ffrag zw = {0.f, 0.f, 0.f, 0.f}, zg = {0.f, 0.f, 0.f, 0.f};
        bfrag bw  = *(const bfrag*)(ws + WS_X0C + ((2 * wave) * 64 + lane) * 8);
        bfrag bgf = *(const bfrag*)(ws + WS_X0C + ((2 * wave + 1) * 64 + lane) * 8);
        zw = mfma16(a, bw, zw);
        zg = mfma16(a, bgf, zg);
#pragma unroll
        for (int r = 0; r < 4; r++) { xcw[r] = zw[r]; xcg[r] = zg[r]; }
    }
    __syncthreads();   // xsb reused for seq staging

    float xwin[4], xgate[4];

    // one RK4 layer update for this WG's 16 rows.
    // Rec weights register-cached at entry (16 frags = 64 VGPRs), asm-pinned so
    // they stay live across all 4 derivs instead of being reloaded from L2.
    auto run_layer = [&](float (*hbuf)[260], __hip_bfloat16 (*A2)[16][APAD],
                         const __hip_bfloat16* __restrict__ rp, float rtpl, int l) {
        bfrag bgc[8], brc[8];
#pragma unroll
        for (int ks = 0; ks < 8; ks++) {
            bgc[ks] = *(const bfrag*)(rp + ((16 * wave + ks) * 64 + lane) * 8);
            brc[ks] = *(const bfrag*)(rp + ((16 * wave + 8 + ks) * 64 + lane) * 8);
        }
#pragma unroll
        for (int ks = 0; ks < 8; ks++) {
            asm volatile("" : "+v"(bgc[ks]));
            asm volatile("" : "+v"(brc[ks]));
        }
        float hbase[4], hh_[4], ksum[4];
#pragma unroll
        for (int r = 0; r < 4; r++) {
            float v = hbuf[qq * 4 + r][col];
            hbase[r] = v; hh_[r] = v; ksum[r] = 0.f;
        }
#pragma unroll 1
        for (int d = 0; d < 4; d++) {
            __syncthreads();
            const __hip_bfloat16 (*A)[APAD] = A2[d & 1];
            ffrag ag = {0.f, 0.f, 0.f, 0.f}, ar = {0.f, 0.f, 0.f, 0.f};
#pragma unroll
            for (int ks = 0; ks < 8; ks++) {
                bfrag a = *(const bfrag*)&A[lm][ks * 32 + qq * 8];
                ag = mfma16(a, bgc[ks], ag);
                ar = mfma16(a, brc[ks], ar);
            }
            float wsm = (d == 1 || d == 2) ? 2.f : 1.f;
            float an  = (d < 2) ? 0.5f : 1.f;
#pragma unroll
            for (int r = 0; r < 4; r++) {
                float g  = fast_sigmoid(fast_tanh(ag[r] + xgate[r]));
                float kd = xwin[r] - hh_[r] * rtpl + g * ar[r];
                ksum[r] += wsm * kd;
                if (d < 3) {
                    float hhn = hbase[r] + an * kd;
                    hh_[r] = hhn;
                    A2[(d & 1) ^ 1][qq * 4 + r][col] = __float2bfloat16(hhn);
                } else {
                    hn[qq * 4 + r][col] = hbase[r] + ksum[r] * (1.f / 6.f);
                }
            }
        }
        __syncthreads();
        // LayerNorm + tanh: wave w handles row w, 4 cols per lane
        {
            int r = wave, c0 = lane * 4;
            float4 vv = *(const float4*)&hn[r][c0];
            float v[4] = {vv.x, vv.y, vv.z, vv.w};
            float s = v[0] + v[1] + v[2] + v[3];
            float s2 = v[0]*v[0] + v[1]*v[1] + v[2]*v[2] + v[3]*v[3];
#pragma unroll
            for (int m = 1; m <= 32; m <<= 1) {
                s  += __shfl_xor(s, m, 64);
                s2 += __shfl_xor(s2, m, 64);
            }
            float mean = s * (1.f / 256.f);
            float var  = s2 * (1.f / 256.f) - mean * mean;
            float rs   = __builtin_amdgcn_rsqf(var + 1e-5f);
            float hv[4];
            __hip_bfloat16 hb[4];
#pragma unroll
            for (int j = 0; j < 4; j++) {
                int c = c0 + j;
                hv[j] = fast_tanh((v[j] - mean) * rs * lnw[l][c] + lnbv[l][c]);
                hb[j] = __float2bfloat16(hv[j]);
            }
            *(float4*)&hbuf[r][c0] = (float4){hv[0], hv[1], hv[2], hv[3]};
            *(uint2*)&A2[0][r][c0] = *(uint2*)hb;   // bf16 A for next use
        }
        __syncthreads();
    };

#pragma unroll 1
    for (int t = 0; t < T_; t++) {
        // stage seq(t) -> xsb bf16 (wave w loads row w, coalesced)
        xsb[wave][lane] = __float2bfloat16(seq[((size_t)(brow + wave) * T_ + t) * FS_ + lane]);
        __syncthreads();
        // layer0 x-projection: seq part (K=64) + ctx constant
        {
            ffrag zw, zg;
#pragma unroll
            for (int r = 0; r < 4; r++) { zw[r] = xcw[r]; zg[r] = xcg[r] + bgr[0]; }
#pragma unroll
            for (int ks = 0; ks < 2; ks++) {
                bfrag a   = *(const bfrag*)&xsb[lm][ks * 32 + qq * 8];
                bfrag bw  = *(const bfrag*)(ws + WS_X0S + ((4 * wave + ks) * 64 + lane) * 8);
                bfrag bg_ = *(const bfrag*)(ws + WS_X0S + ((4 * wave + 2 + ks) * 64 + lane) * 8);
                zw = mfma16(a, bw, zw);
                zg = mfma16(a, bg_, zg);
            }
#pragma unroll
            for (int r = 0; r < 4; r++) { xwin[r] = zw[r]; xgate[r] = zg[r]; }
        }
        run_layer(h0, abf0, ws + WS_REC0, rtp[0], 0);
        // layer1 x-projection from h0_new (bf16 already in abf0[0]), K=256
        {
            ffrag zw = {0.f, 0.f, 0.f, 0.f}, zg;
#pragma unroll
            for (int r = 0; r < 4; r++) zg[r] = bgr[1];
#pragma unroll
            for (int ks = 0; ks < 8; ks++) {
                bfrag a   = *(const bfrag*)&abf0[0][lm][ks * 32 + qq * 8];
                bfrag bw  = *(const bfrag*)(ws + WS_X1P + ((16 * wave + ks) * 64 + lane) * 8);
                bfrag bg_ = *(const bfrag*)(ws + WS_X1P + ((16 * wave + 8 + ks) * 64 + lane) * 8);
                zw = mfma16(a, bw, zw);
                zg = mfma16(a, bg_, zg);
            }
#pragma unroll
            for (int r = 0; r < 4; r++) { xwin[r] = zw[r]; xgate[r] = zg[r]; }
        }
        run_layer(h1, abf1, ws + WS_REC1, rtp[1], 1);
    }

    // ---- head: hid = relu(h1 @ cW1^T + cb1); out = hid @ cW2^T + cb2 ----
    {
        int r = wave;                 // wave w handles batch row w; lane -> 2 outputs
        float acc0 = cb1[lane], acc1 = cb1[lane + 64];
        const float* w0 = cW1 + (size_t)lane * H_;
        const float* w1 = cW1 + (size_t)(lane + 64) * H_;
        for (int k = 0; k < H_; k += 4) {
            float4 hv = *(const float4*)&h1[r][k];
            acc0 += hv.x * w0[k] + hv.y * w0[k+1] + hv.z * w0[k+2] + hv.w * w0[k+3];
            acc1 += hv.x * w1[k] + hv.y * w1[k+1] + hv.z * w1[k+2] + hv.w * w1[k+3];
        }
        __syncthreads();
        hn[r][lane]      = fmaxf(acc0, 0.f);
        hn[r][lane + 64] = fmaxf(acc1, 0.f);
    }
    __syncthreads();
    if (tid < 16) {
        float acc = cb2[0];
        for (int k = 0; k < 128; k++) acc += hn[tid][k] * cW2[k];
        out[brow + tid] = acc;
    }
}

extern "C" void kernel_launch(void* const* d_in, const int* in_sizes, int n_in,
                              void* d_out, int out_size, void* d_ws, size_t ws_size,
                              hipStream_t stream) {
    const float* seq   = (const float*)d_in[0];
    const float* ctx   = (const float*)d_in[1];
    const float* tau0  = (const float*)d_in[2];
    const float* Win0  = (const float*)d_in[3];
    const float* Wrec0 = (const float*)d_in[4];
    const float* Wg0   = (const float*)d_in[5];
    const float* bg0   = (const float*)d_in[6];
    const float* lng0  = (const float*)d_in[7];
    const float* lnb0  = (const float*)d_in[8];
    const float* tau1  = (const float*)d_in[9];
    const float* Win1  = (const float*)d_in[10];
    const float* Wrec1 = (const float*)d_in[11];
    const float* Wg1   = (const float*)d_in[12];
    const float* bg1   = (const float*)d_in[13];
    const float* lng1  = (const float*)d_in[14];
    const float* lnb1  = (const float*)d_in[15];
    const float* cW1   = (const float*)d_in[16];
    const float* cb1   = (const float*)d_in[17];
    const float* cW2   = (const float*)d_in[18];
    const float* cb2   = (const float*)d_in[19];
    __hip_bfloat16* ws = (__hip_bfloat16*)d_ws;

    hipLaunchKernelGGL(prepack_kernel, dim3(216), dim3(256), 0, stream,
                       Win0, Wrec0, Wg0, Win1, Wrec1, Wg1, ws);
    hipLaunchKernelGGL(lnn_main, dim3(32), dim3(1024), 0, stream,
                       seq, ctx, tau0, bg0, lng0, lnb0, tau1, bg1, lng1, lnb1,
                       cW1, cb1, cW2, cb2, ws, (float*)d_out);
}

// Round 6
// 13502.216 us; speedup vs baseline: 1.7575x; 1.2008x over previous
//
#include <hip/hip_runtime.h>
#include <hip/hip_bf16.h>

#define B_  512
#define T_  512
#define FS_ 64
#define FC_ 32
#define H_  256
#define APAD 272   // empirically best (R4: 1.26e7 conflicts vs 7.55e7 at 264)

// ws layout (bf16 element offsets)
#define WS_REC0 0        // [32 ft][8 ks][64 lane][8]   even ft = Wg_h, odd = Wrec
#define WS_REC1 131072
#define WS_X1P  262144   // [32][8][64][8]              even ft = Win1, odd = Wg_x1
#define WS_X0S  393216   // [32][2][64][8]              even ft = Win0, odd = Wg_x0
#define WS_X0C  425984   // [32][1][64][8]              even ft = Win0c, odd = Wg_x0c

typedef __attribute__((ext_vector_type(8))) short bfrag;
typedef __attribute__((ext_vector_type(4))) float ffrag;

__device__ __forceinline__ ffrag mfma16(bfrag a, bfrag b, ffrag c) {
    return __builtin_amdgcn_mfma_f32_16x16x32_bf16(a, b, c, 0, 0, 0);
}
__device__ __forceinline__ float fast_tanh(float x) {
    float e = __builtin_amdgcn_exp2f(x * 2.8853901817f);   // exp(2x), inf-safe
    return 1.f - 2.f * __builtin_amdgcn_rcpf(e + 1.f);
}
// LDS-only barrier: drains LDS (correctness for shared tiles) but leaves global
// loads in flight -> weight prefetch survives across rounds (m97 lesson).
__device__ __forceinline__ void bar_lds() {
    asm volatile("s_waitcnt lgkmcnt(0)\n\ts_barrier" ::: "memory");
}

// ---------------- prepack: fp32 weights -> bf16 MFMA B-fragments ----------------
__global__ __launch_bounds__(256) void prepack_kernel(
    const float* __restrict__ Win0, const float* __restrict__ Wrec0, const float* __restrict__ Wg0,
    const float* __restrict__ Win1, const float* __restrict__ Wrec1, const float* __restrict__ Wg1,
    __hip_bfloat16* __restrict__ ws)
{
    int g = blockIdx.x * 256 + threadIdx.x;
    if (g >= 55296) return;
    int lane = g & 63;
    int frag = g >> 6;               // 0..863
    int lm = lane & 15, qq = lane >> 4;
    const float* src;
    int dstoff;
    if (frag < 256) {
        int f = frag, ft = f >> 3, ks = f & 7;
        int n = (ft >> 1) * 16 + lm, kk = ks * 32 + qq * 8;
        src = (ft & 1) ? (Wrec0 + n * 256 + kk) : (Wg0 + n * 352 + 96 + kk);
        dstoff = WS_REC0 + (f * 64 + lane) * 8;
    } else if (frag < 512) {
        int f = frag - 256, ft = f >> 3, ks = f & 7;
        int n = (ft >> 1) * 16 + lm, kk = ks * 32 + qq * 8;
        src = (ft & 1) ? (Wrec1 + n * 256 + kk) : (Wg1 + n * 512 + 256 + kk);
        dstoff = WS_REC1 + (f * 64 + lane) * 8;
    } else if (frag < 768) {
        int f = frag - 512, ft = f >> 3, ks = f & 7;
        int n = (ft >> 1) * 16 + lm, kk = ks * 32 + qq * 8;
        src = (ft & 1) ? (Wg1 + n * 512 + kk) : (Win1 + n * 256 + kk);
        dstoff = WS_X1P + (f * 64 + lane) * 8;
    } else if (frag < 832) {
        int f = frag - 768, ft = f >> 1, ks = f & 1;
        int n = (ft >> 1) * 16 + lm, kk = ks * 32 + qq * 8;
        src = (ft & 1) ? (Wg0 + n * 352 + kk) : (Win0 + n * 96 + kk);
        dstoff = WS_X0S + (f * 64 + lane) * 8;
    } else {
        int f = frag - 832, ft = f;
        int n = (ft >> 1) * 16 + lm, kk = qq * 8;
        src = (ft & 1) ? (Wg0 + n * 352 + 64 + kk) : (Win0 + n * 96 + 64 + kk);
        dstoff = WS_X0C + (f * 64 + lane) * 8;
    }
    __hip_bfloat16* d = ws + dstoff;
#pragma unroll
    for (int j = 0; j < 8; j++) d[j] = __float2bfloat16(src[j]);
}

// ---------------- main persistent kernel: 32 WGs x 16 batch rows ----------------
__global__ __launch_bounds__(1024, 4) void lnn_main(
    const float* __restrict__ seq, const float* __restrict__ ctx,
    const float* __restrict__ tau0, const float* __restrict__ bg0,
    const float* __restrict__ lng0, const float* __restrict__ lnb0,
    const float* __restrict__ tau1, const float* __restrict__ bg1,
    const float* __restrict__ lng1, const float* __restrict__ lnb1,
    const float* __restrict__ cW1, const float* __restrict__ cb1,
    const float* __restrict__ cW2, const float* __restrict__ cb2,
    const __hip_bfloat16* __restrict__ ws, float* __restrict__ out)
{
    __shared__ __align__(16) float h0[16][260];
    __shared__ __align__(16) float h1[16][260];
    __shared__ __align__(16) float hn[16][260];
    __shared__ __align__(16) __hip_bfloat16 abf0[2][16][APAD];
    __shared__ __align__(16) __hip_bfloat16 abf1[2][16][APAD];
    __shared__ __align__(16) __hip_bfloat16 xsb[16][80];
    __shared__ __align__(16) float lnw[2][256], lnbv[2][256];

    const int tid  = threadIdx.x;
    const int wave = tid >> 6, lane = tid & 63;
    const int qq   = lane >> 4, lm = lane & 15;
    const int brow = blockIdx.x * 16;
    const int col  = wave * 16 + lm;

    for (int e = tid; e < 16 * 260; e += 1024) { ((float*)h0)[e] = 0.f; ((float*)h1)[e] = 0.f; }
    for (int e = tid; e < 2 * 16 * APAD; e += 1024) {
        ((__hip_bfloat16*)abf0)[e] = __float2bfloat16(0.f);
        ((__hip_bfloat16*)abf1)[e] = __float2bfloat16(0.f);
    }
    for (int c = tid; c < 256; c += 1024) {
        lnw[0][c] = lng0[c]; lnw[1][c] = lng1[c];
        lnbv[0][c] = lnb0[c]; lnbv[1][c] = lnb1[c];
    }
    float rtp[2], bgr[2];
    {
        float t0v = tau0[col], t1v = tau1[col];
        float sp0 = fmaxf(t0v, 0.f) + logf(1.f + __expf(-fabsf(t0v)));
        float sp1 = fmaxf(t1v, 0.f) + logf(1.f + __expf(-fabsf(t1v)));
        rtp[0] = 1.f / (sp0 + 1.f);
        rtp[1] = 1.f / (sp1 + 1.f);
        bgr[0] = bg0[col]; bgr[1] = bg1[col];
    }
    for (int e = tid; e < 16 * FC_; e += 1024) {
        int r = e >> 5, c = e & 31;
        xsb[r][c] = __float2bfloat16(ctx[(brow + r) * FC_ + c]);
    }
    __syncthreads();
    float xcw[4], xcg[4];
    {
        bfrag a = *(const bfrag*)&xsb[lm][qq * 8];
        ffrag zw = {0.f, 0.f, 0.f, 0.f}, zg = {0.f, 0.f, 0.f, 0.f};
        bfrag bw  = *(const bfrag*)(ws + WS_X0C + ((2 * wave) * 64 + lane) * 8);
        bfrag bgf = *(const bfrag*)(ws + WS_X0C + ((2 * wave + 1) * 64 + lane) * 8);
        zw = mfma16(a, bw, zw);
        zg = mfma16(a, bgf, zg);
#pragma unroll
        for (int r = 0; r < 4; r++) { xcw[r] = zw[r]; xcg[r] = zg[r]; }
    }
    __syncthreads();

    // ---- pipeline state (loop-carried registers) ----
    bfrag cg[8], cr[8];          // current layer's rec/gate B-frag cache
    bfrag xpw[8], xpg[8];        // x1 projection staging
    float xwin[4], xgate[4];
    float hbase[4], hh[4], ksum[4];
    float seqv;

    auto fillrec = [&](const __hip_bfloat16* __restrict__ rp) {
#pragma unroll
        for (int ks = 0; ks < 8; ks++) {
            cg[ks] = *(const bfrag*)(rp + ((16 * wave + ks) * 64 + lane) * 8);
            cr[ks] = *(const bfrag*)(rp + ((16 * wave + 8 + ks) * 64 + lane) * 8);
        }
    };
    auto pinrec = [&]() {
#pragma unroll
        for (int ks = 0; ks < 8; ks++) {
            asm volatile("" : "+v"(cg[ks]));
            asm volatile("" : "+v"(cr[ks]));
        }
    };
    // one RK4 deriv round. extra: 1 = issue x1p prefetch, 2 = issue rec0(t+1) fill
    auto deriv = [&](const __hip_bfloat16 (*Ar)[APAD], __hip_bfloat16 (*Aw)[APAD],
                     int d, float rtpl, int extra) {
        ffrag ag = {0.f, 0.f, 0.f, 0.f}, ar = {0.f, 0.f, 0.f, 0.f};
#pragma unroll
        for (int ks = 0; ks < 8; ks++) {
            bfrag a = *(const bfrag*)&Ar[lm][ks * 32 + qq * 8];
            ag = mfma16(a, cg[ks], ag);
            ar = mfma16(a, cr[ks], ar);
        }
        if (extra == 1) {
#pragma unroll
            for (int ks = 0; ks < 8; ks++) {
                xpw[ks] = *(const bfrag*)(ws + WS_X1P + ((16 * wave + ks) * 64 + lane) * 8);
                xpg[ks] = *(const bfrag*)(ws + WS_X1P + ((16 * wave + 8 + ks) * 64 + lane) * 8);
            }
        } else if (extra == 2) {
            fillrec(ws + WS_REC0);
        }
        float wsm = (d == 1 || d == 2) ? 2.f : 1.f;
        float an  = (d < 2) ? 0.5f : 1.f;
#pragma unroll
        for (int r = 0; r < 4; r++) {
            float t  = fast_tanh(ag[r] + xgate[r]);
            float t2 = t * t;
            // sigmoid(t) on t in (-1,1): odd series, err <= 2.1e-4
            float g  = 0.5f + t * (0.25f + t2 * (-(1.f / 48.f) + t2 * (1.f / 480.f)));
            float kd = xwin[r] - hh[r] * rtpl + g * ar[r];
            ksum[r] += wsm * kd;
            if (d < 3) {
                float hhn = hbase[r] + an * kd;
                hh[r] = hhn;
                Aw[qq * 4 + r][col] = __float2bfloat16(hhn);
            } else {
                hn[qq * 4 + r][col] = hbase[r] + ksum[r] * (1.f / 6.f);
            }
        }
    };
    auto lnorm = [&](float (*hbuf)[260], __hip_bfloat16 (*A0)[APAD], int l) {
        int r = wave, c0 = lane * 4;
        float4 vv = *(const float4*)&hn[r][c0];
        float v[4] = {vv.x, vv.y, vv.z, vv.w};
        float s  = v[0] + v[1] + v[2] + v[3];
        float s2 = v[0]*v[0] + v[1]*v[1] + v[2]*v[2] + v[3]*v[3];
#pragma unroll
        for (int m = 1; m <= 32; m <<= 1) {
            s  += __shfl_xor(s, m, 64);
            s2 += __shfl_xor(s2, m, 64);
        }
        float mean = s * (1.f / 256.f);
        float var  = s2 * (1.f / 256.f) - mean * mean;
        float rs   = __builtin_amdgcn_rsqf(var + 1e-5f);
        float4 lw = *(const float4*)&lnw[l][c0];
        float4 lb = *(const float4*)&lnbv[l][c0];
        float hv[4];
        __hip_bfloat16 hb[4];
        hv[0] = fast_tanh((v[0] - mean) * rs * lw.x + lb.x);
        hv[1] = fast_tanh((v[1] - mean) * rs * lw.y + lb.y);
        hv[2] = fast_tanh((v[2] - mean) * rs * lw.z + lb.z);
        hv[3] = fast_tanh((v[3] - mean) * rs * lw.w + lb.w);
#pragma unroll
        for (int j = 0; j < 4; j++) hb[j] = __float2bfloat16(hv[j]);
        *(float4*)&hbuf[r][c0] = (float4){hv[0], hv[1], hv[2], hv[3]};
        *(uint2*)&A0[r][c0] = *(uint2*)hb;
    };

    fillrec(ws + WS_REC0);                                   // rec0 for t=0
    seqv = seq[((size_t)(brow + wave) * T_ + 0) * FS_ + lane];

#pragma unroll 1
    for (int t = 0; t < T_; t++) {
        xsb[wave][lane] = __float2bfloat16(seqv);
        bar_lds();
        // ---- ROUND A: x0 projection + L0 deriv0 ----
        {
            bfrag b0w[2], b0g[2];
#pragma unroll
            for (int ks = 0; ks < 2; ks++) {
                b0w[ks] = *(const bfrag*)(ws + WS_X0S + ((4 * wave + ks) * 64 + lane) * 8);
                b0g[ks] = *(const bfrag*)(ws + WS_X0S + ((4 * wave + 2 + ks) * 64 + lane) * 8);
            }
            pinrec();   // rec0 (prefetched last iter / pre-loop)
            ffrag zw, zg;
#pragma unroll
            for (int r = 0; r < 4; r++) { zw[r] = xcw[r]; zg[r] = xcg[r] + bgr[0]; }
#pragma unroll
            for (int ks = 0; ks < 2; ks++) {
                bfrag a = *(const bfrag*)&xsb[lm][ks * 32 + qq * 8];
                zw = mfma16(a, b0w[ks], zw);
                zg = mfma16(a, b0g[ks], zg);
            }
#pragma unroll
            for (int r = 0; r < 4; r++) { xwin[r] = zw[r]; xgate[r] = zg[r]; }
#pragma unroll
            for (int r = 0; r < 4; r++) {
                float v = h0[qq * 4 + r][col];
                hbase[r] = v; hh[r] = v; ksum[r] = 0.f;
            }
            int tn = (t + 1 < T_) ? t + 1 : t;
            seqv = seq[((size_t)(brow + wave) * T_ + tn) * FS_ + lane];   // prefetch
            deriv(abf0[0], abf0[1], 0, rtp[0], 0);
        }
        bar_lds();
        deriv(abf0[1], abf0[0], 1, rtp[0], 0);
        bar_lds();
        deriv(abf0[0], abf0[1], 2, rtp[0], 0);
        bar_lds();
        deriv(abf0[1], abf0[0], 3, rtp[0], 1);   // + x1p prefetch
        bar_lds();
        lnorm(h0, abf0[0], 0);
        bar_lds();
        // ---- x1 projection (consume xp*), then rec1 fill, then L1 deriv0 ----
        {
#pragma unroll
            for (int ks = 0; ks < 8; ks++) {
                asm volatile("" : "+v"(xpw[ks]));
                asm volatile("" : "+v"(xpg[ks]));
            }
            ffrag zw = {0.f, 0.f, 0.f, 0.f}, zg;
#pragma unroll
            for (int r = 0; r < 4; r++) zg[r] = bgr[1];
#pragma unroll
            for (int ks = 0; ks < 8; ks++) {
                bfrag a = *(const bfrag*)&abf0[0][lm][ks * 32 + qq * 8];
                zw = mfma16(a, xpw[ks], zw);
                zg = mfma16(a, xpg[ks], zg);
            }
#pragma unroll
            for (int r = 0; r < 4; r++) { xwin[r] = zw[r]; xgate[r] = zg[r]; }
            fillrec(ws + WS_REC1);
#pragma unroll
            for (int r = 0; r < 4; r++) {
                float v = h1[qq * 4 + r][col];
                hbase[r] = v; hh[r] = v; ksum[r] = 0.f;
            }
            pinrec();   // rec1
            deriv(abf1[0], abf1[1], 0, rtp[1], 0);
        }
        bar_lds();
        deriv(abf1[1], abf1[0], 1, rtp[1], 0);
        bar_lds();
        deriv(abf1[0], abf1[1], 2, rtp[1], 0);
        bar_lds();
        deriv(abf1[1], abf1[0], 3, rtp[1], 2);   // + rec0(t+1) fill
        bar_lds();
        lnorm(h1, abf1[0], 1);
        bar_lds();
    }

    __syncthreads();
    // ---- head: hid = relu(h1 @ cW1^T + cb1); out = hid @ cW2^T + cb2 ----
    {
        int r = wave;
        float acc0 = cb1[lane], acc1 = cb1[lane + 64];
        const float* w0 = cW1 + (size_t)lane * H_;
        const float* w1 = cW1 + (size_t)(lane + 64) * H_;
        for (int k = 0; k < H_; k += 4) {
            float4 hv = *(const float4*)&h1[r][k];
            acc0 += hv.x * w0[k] + hv.y * w0[k+1] + hv.z * w0[k+2] + hv.w * w0[k+3];
            acc1 += hv.x * w1[k] + hv.y * w1[k+1] + hv.z * w1[k+2] + hv.w * w1[k+3];
        }
        __syncthreads();
        hn[r][lane]      = fmaxf(acc0, 0.f);
        hn[r][lane + 64] = fmaxf(acc1, 0.f);
    }
    __syncthreads();
    if (tid < 16) {
        float acc = cb2[0];
        for (int k = 0; k < 128; k++) acc += hn[tid][k] * cW2[k];
        out[brow + tid] = acc;
    }
}

extern "C" void kernel_launch(void* const* d_in, const int* in_sizes, int n_in,
                              void* d_out, int out_size, void* d_ws, size_t ws_size,
                              hipStream_t stream) {
    const float* seq   = (const float*)d_in[0];
    const float* ctx   = (const float*)d_in[1];
    const float* tau0  = (const float*)d_in[2];
    const float* Win0  = (const float*)d_in[3];
    const float* Wrec0 = (const float*)d_in[4];
    const float* Wg0   = (const float*)d_in[5];
    const float* bg0   = (const float*)d_in[6];
    const float* lng0  = (const float*)d_in[7];
    const float* lnb0  = (const float*)d_in[8];
    const float* tau1  = (const float*)d_in[9];
    const float* Win1  = (const float*)d_in[10];
    const float* Wrec1 = (const float*)d_in[11];
    const float* Wg1   = (const float*)d_in[12];
    const float* bg1   = (const float*)d_in[13];
    const float* lng1  = (const float*)d_in[14];
    const float* lnb1  = (const float*)d_in[15];
    const float* cW1   = (const float*)d_in[16];
    const float* cb1   = (const float*)d_in[17];
    const float* cW2   = (const float*)d_in[18];
    const float* cb2   = (const float*)d_in[19];
    __hip_bfloat16* ws = (__hip_bfloat16*)d_ws;

    hipLaunchKernelGGL(prepack_kernel, dim3(216), dim3(256), 0, stream,
                       Win0, Wrec0, Wg0, Win1, Wrec1, Wg1, ws);
    hipLaunchKernelGGL(lnn_main, dim3(32), dim3(1024), 0, stream,
                       seq, ctx, tau0, bg0, lng0, lnb0, tau1, bg1, lng1, lnb1,
                       cW1, cb1, cW2, cb2, ws, (float*)d_out);
}